// Round 14
// baseline (527.011 us; speedup 1.0000x reference)
//
#include <hip/hip_runtime.h>

#define B_   2
#define S_   2048
#define D_   4096
#define H_   32
#define KVH_ 8
#define HD_  128
#define NE_  6144   // (KVH*2+H)*HD

using f32x4  = __attribute__((ext_vector_type(4))) float;
using bf16x8 = __attribute__((ext_vector_type(8))) __bf16;
using u16x8  = __attribute__((ext_vector_type(8))) unsigned short;

__device__ __forceinline__ unsigned short f2bf(float f) {
  union { float f; unsigned u; } v; v.f = f;
  unsigned r = v.u + 0x7FFFu + ((v.u >> 16) & 1u);
  return (unsigned short)(r >> 16);
}
__device__ __forceinline__ float bf2f(unsigned short h) {
  union { unsigned u; float f; } v; v.u = ((unsigned)h) << 16; return v.f;
}
__device__ __forceinline__ bf16x8 ld8(const unsigned short* p) {
  return *reinterpret_cast<const bf16x8*>(p);
}
__device__ __forceinline__ bf16x8 ld8b(const void* base, int byte_off) {
  return *reinterpret_cast<const bf16x8*>((const char*)base + byte_off);
}
__device__ __forceinline__ void cp16(const void* g, void* l) {
  __builtin_amdgcn_global_load_lds(
      (const __attribute__((address_space(1))) void*)g,
      (__attribute__((address_space(3))) void*)l, 16, 0, 0);
}
__device__ __forceinline__ float exp2a(float x) {   // 2^x via v_exp_f32
  float r; asm("v_exp_f32 %0, %1" : "=v"(r) : "v"(x)); return r;
}

#define SC2F 0.12751652f   // (1/sqrt(128)) * log2(e)

// ---------------------------------------------------------------------------
// Two segments in one launch (dests must be disjoint!).
// ---------------------------------------------------------------------------
__global__ __launch_bounds__(256) void cvt2_f32_bf16(
    const float* __restrict__ s0, unsigned short* __restrict__ d0, int n0,
    const float* __restrict__ s1, unsigned short* __restrict__ d1, int n1)
{
  int i = blockIdx.x * 256 + threadIdx.x;
  const float* src; unsigned short* dst;
  if (i < n0) { src = s0; dst = d0; }
  else        { i -= n0; if (i >= n1) return; src = s1; dst = d1; }
  f32x4 v = *reinterpret_cast<const f32x4*>(src + (size_t)i * 4);
  ushort4 o;
  o.x = f2bf(v[0]); o.y = f2bf(v[1]); o.z = f2bf(v[2]); o.w = f2bf(v[3]);
  *reinterpret_cast<ushort4*>(dst + (size_t)i * 4) = o;
}

// ---------------------------------------------------------------------------
// 256xNT-tile 8-phase GEMM: C[M,N] = A[M,K] * B[N,K]^T, K=4096 fixed.
// r14: stages shifted one phase earlier (A x4 @P1, B @P2/P3; P4 stage-free)
// -- identical vmcnt proofs (P4: 12 outstanding, vmcnt(4) proves B(t1)+A(t1);
// P8 symmetric; NT=192: 10 outstanding, vmcnt(3) proves 7), but every load
// gets >=1 extra phase in flight before its proof point.
// ---------------------------------------------------------------------------
template <typename OutT, int NT>
__global__ __launch_bounds__(512, 2) void gemm256(
    const unsigned short* __restrict__ A,
    const unsigned short* __restrict__ Bw,
    OutT* __restrict__ C, int M, int N)
{
  constexpr int K  = 4096;
  constexpr int NI = (K / 64) / 2;     // 32 iterations, 2 K-tiles each
  constexpr int NB = NT / 64;          // B chunks per tile (3 or 4)
  constexpr int NN = NT / 64;          // n-frags per wave
  constexpr int WN = NT / 4;           // per-wave N extent
  constexpr int BBUF = NT * 128;       // B bytes per buffer
  __shared__ __align__(16) char lds[65536 + 2 * BBUF];

  const int tid  = threadIdx.x;
  const int lane = tid & 63;
  const int wave = tid >> 6;
  const int wr = wave >> 2;            // 0..1  (M half)
  const int wc = wave & 3;             // 0..3  (N quarter)
  const int lr = lane & 15;
  const int lk = (lane >> 4) * 8;

  int id  = blockIdx.y * gridDim.x + blockIdx.x;
  const int nwg = gridDim.x * gridDim.y;
  if ((nwg & 7) == 0) { const int q = nwg >> 3; id = (id & 7) * q + (id >> 3); }
  const int row0 = (id / gridDim.x) * 256;
  const int col0 = (id % gridDim.x) * NT;

  // A staging: 2 halves x 2 loads/thread (16KB each).
  int rwA[2], csA[2], dbA[2];
#pragma unroll
  for (int j = 0; j < 2; ++j) {
    dbA[j] = j * 8192 + tid * 16;
    rwA[j] = dbA[j] >> 7;
    csA[j] = ((dbA[j] & 127) ^ ((rwA[j] & 7) << 4)) >> 1;
  }
  auto stA = [&](int buf, int h, int t) {
#pragma unroll
    for (int j = 0; j < 2; ++j)
      cp16(A + (size_t)(row0 + h * 128 + rwA[j]) * K + t * 64 + csA[j],
           lds + buf * 32768 + h * 16384 + dbA[j]);
  };
  // B staging: NB chunks x 1 load/thread (8KB each, 64 rows).
  const int dbB = tid * 16;
  const int rwB = dbB >> 7;                              // 0..63
  const int csB = ((dbB & 127) ^ ((rwB & 7) << 4)) >> 1; // chunk row base %8==0
  auto stB = [&](int buf, int c, int t) {
    cp16(Bw + (size_t)(col0 + c * 64 + rwB) * K + t * 64 + csB,
         lds + 65536 + buf * BBUF + c * 8192 + dbB);
  };

  const int cb0 = ((0 + lk) << 1) ^ ((lr & 7) << 4);
  const int cb1 = ((32 + lk) << 1) ^ ((lr & 7) << 4);
  const int aRowB = (wr * 128 + lr) * 128;
  const int bRowB = (wc * WN + lr) * 128;

  f32x4 acc[8][NN];
#pragma unroll
  for (int m = 0; m < 8; ++m)
#pragma unroll
    for (int n = 0; n < NN; ++n) acc[m][n] = (f32x4){0.f, 0.f, 0.f, 0.f};
  bf16x8 bfr[NN][2];

#define FENCE asm volatile("" ::: "memory")
#define VMNB  do { if constexpr (NB == 4) asm volatile("s_waitcnt vmcnt(4)" ::: "memory"); \
                   else                   asm volatile("s_waitcnt vmcnt(3)" ::: "memory"); } while (0)
#define VM0   asm volatile("s_waitcnt vmcnt(0)" ::: "memory")

#define PHASE(p, buf, STAGE, WAIT)                                             \
  {                                                                            \
    if ((p) == 0) {                                                            \
      _Pragma("unroll")                                                        \
      for (int n = 0; n < NN; ++n) {                                           \
        bfr[n][0] = ld8b(lds, 65536 + (buf) * BBUF + bRowB + n * 2048 + cb0);  \
        bfr[n][1] = ld8b(lds, 65536 + (buf) * BBUF + bRowB + n * 2048 + cb1);  \
      }                                                                        \
    }                                                                          \
    bf16x8 a00 = ld8b(lds, (buf) * 32768 + aRowB + ((p) * 2 + 0) * 2048 + cb0);\
    bf16x8 a01 = ld8b(lds, (buf) * 32768 + aRowB + ((p) * 2 + 0) * 2048 + cb1);\
    bf16x8 a10 = ld8b(lds, (buf) * 32768 + aRowB + ((p) * 2 + 1) * 2048 + cb0);\
    bf16x8 a11 = ld8b(lds, (buf) * 32768 + aRowB + ((p) * 2 + 1) * 2048 + cb1);\
    STAGE;                                                                     \
    FENCE;                                                                     \
    __builtin_amdgcn_s_barrier();                                              \
    __builtin_amdgcn_s_setprio(1);                                             \
    _Pragma("unroll")                                                          \
    for (int n = 0; n < NN; ++n) {                                             \
      acc[(p)*2+0][n] = __builtin_amdgcn_mfma_f32_16x16x32_bf16(a00, bfr[n][0], acc[(p)*2+0][n], 0, 0, 0); \
      acc[(p)*2+0][n] = __builtin_amdgcn_mfma_f32_16x16x32_bf16(a01, bfr[n][1], acc[(p)*2+0][n], 0, 0, 0); \
      acc[(p)*2+1][n] = __builtin_amdgcn_mfma_f32_16x16x32_bf16(a10, bfr[n][0], acc[(p)*2+1][n], 0, 0, 0); \
      acc[(p)*2+1][n] = __builtin_amdgcn_mfma_f32_16x16x32_bf16(a11, bfr[n][1], acc[(p)*2+1][n], 0, 0, 0); \
    }                                                                          \
    __builtin_amdgcn_s_setprio(0);                                             \
    WAIT;                                                                      \
    FENCE;                                                                     \
    __builtin_amdgcn_s_barrier();                                              \
  }

  // Prologue: tile0 B+A into buf0, tile1 B into buf1; allow tile1-B in flight.
#pragma unroll
  for (int c = 0; c < NB; ++c) stB(0, c, 0);
  stA(0, 0, 0); stA(0, 1, 0);
#pragma unroll
  for (int c = 0; c < NB; ++c) stB(1, c, 1);
  VMNB;
  FENCE;
  __builtin_amdgcn_s_barrier();

  for (int i = 0; i < NI; ++i) {
    const int t1  = 2 * i + 1;
    const int tn0 = 2 * i + 2;
    const int tn1 = 2 * i + 3;
    const bool pre = (i + 1 < NI);
    // K-tile 2i in buf0 (stages one phase earlier than r13; proofs identical)
    PHASE(0, 0, { stA(1, 0, t1); stA(1, 1, t1); }, {});
    PHASE(1, 0, { if (pre) { stB(0, 0, tn0); stB(0, 1, tn0); } }, {});
    PHASE(2, 0, { if (pre) { _Pragma("unroll") for (int c = 2; c < NB; ++c) stB(0, c, tn0); } }, {});
    PHASE(3, 0, {}, { if (pre) { VMNB; } else { VM0; } });
    // K-tile 2i+1 in buf1
    PHASE(0, 1, { if (pre) { stA(0, 0, tn0); stA(0, 1, tn0); } }, {});
    PHASE(1, 1, { if (pre) { stB(1, 0, tn1); stB(1, 1, tn1); } }, {});
    PHASE(2, 1, { if (pre) { _Pragma("unroll") for (int c = 2; c < NB; ++c) stB(1, c, tn1); } }, {});
    PHASE(3, 1, {}, { if (pre) { VMNB; } });
  }
#undef PHASE
#undef FENCE
#undef VMNB
#undef VM0

  const int orow = (lane >> 4) * 4;
#pragma unroll
  for (int m = 0; m < 8; ++m) {
    const int gr0 = row0 + wr * 128 + m * 16 + orow;
#pragma unroll
    for (int n = 0; n < NN; ++n) {
      const int gc = col0 + wc * WN + n * 16 + lr;
#pragma unroll
      for (int r = 0; r < 4; ++r) {
        float val = acc[m][n][r];
        if constexpr (sizeof(OutT) == 2)
          C[(size_t)(gr0 + r) * N + gc] = f2bf(val);
        else
          C[(size_t)(gr0 + r) * N + gc] = val;
      }
    }
  }
}

// ---------------------------------------------------------------------------
// Fused: (a) rope_scatter of fused[B,S,48,128] -> Qr (rope, pre-scaled by
// SC2 = scale*log2e), Kr (rope), Vt (transposed); (b) wdense fp32->bf16 cvt.
// Both run after GEMM1; disjoint outputs -> safe in one launch.
// ---------------------------------------------------------------------------
#define ROPE_N (B_ * S_ * 48 * 8)
__global__ __launch_bounds__(256) void rope_scatter_cvt(
    const unsigned short* __restrict__ fused,
    unsigned short* __restrict__ Qr,
    unsigned short* __restrict__ Kr,
    unsigned short* __restrict__ Vt,
    const float* __restrict__ wdense,
    unsigned short* __restrict__ Wdb,
    int nD4)
{
  int idx = blockIdx.x * 256 + threadIdx.x;
  if (idx >= ROPE_N) {   // wdense conversion range
    int i = idx - ROPE_N;
    if (i >= nD4) return;
    f32x4 v = *reinterpret_cast<const f32x4*>(wdense + (size_t)i * 4);
    ushort4 o;
    o.x = f2bf(v[0]); o.y = f2bf(v[1]); o.z = f2bf(v[2]); o.w = f2bf(v[3]);
    *reinterpret_cast<ushort4*>(Wdb + (size_t)i * 4) = o;
    return;
  }
  int dg = idx & 7;            // d = dg*8 + jj
  int t = idx >> 3;
  int e = t % 48;
  int bs = t / 48;
  int s = bs % S_;
  int b = bs / S_;
  int kvh = e / 6, j = e % 6;
  const unsigned short* src = fused + (size_t)bs * NE_ + e * 128 + dg * 8;
  u16x8 lo = *reinterpret_cast<const u16x8*>(src);
  u16x8 hi = *reinterpret_cast<const u16x8*>(src + 64);
  if (j == 5) {  // V: transposed store
    size_t base = (size_t)(b * KVH_ + kvh) * HD_ * S_ + s;
#pragma unroll
    for (int jj = 0; jj < 8; ++jj) {
      Vt[base + (size_t)(dg * 8 + jj) * S_]      = lo[jj];
      Vt[base + (size_t)(dg * 8 + jj + 64) * S_] = hi[jj];
    }
  } else {
    const float sc = (j == 4) ? 1.0f : SC2F;   // Q heads pre-scaled
    u16x8 olo, ohi;
#pragma unroll
    for (int jj = 0; jj < 8; ++jj) {
      int d = dg * 8 + jj;
      float x1 = bf2f(lo[jj]), x2 = bf2f(hi[jj]);
      float inv = __expf(-(float)d * (9.2103403719761836f / 64.0f));
      float ang = (float)s * inv;
      float sn, c;
      sincosf(ang, &sn, &c);
      olo[jj] = f2bf((x1 * c - x2 * sn) * sc);
      ohi[jj] = f2bf((x2 * c + x1 * sn) * sc);
    }
    unsigned short* dst;
    if (j == 4) dst = Kr + ((size_t)(b * KVH_ + kvh) * S_ + s) * HD_;
    else        dst = Qr + ((size_t)(b * H_ + kvh * 4 + j) * S_ + s) * HD_;
    *reinterpret_cast<u16x8*>(dst + dg * 8)      = olo;
    *reinterpret_cast<u16x8*>(dst + dg * 8 + 64) = ohi;
  }
}

// ---------------------------------------------------------------------------
// Causal GQA flash attention (round-10/13 structure, Q pre-scaled upstream):
// QBLK=64 (4 waves x 16 q-rows), K/V dbuf (72 KB -> 2 blocks/CU),
// prefetch-first, one barrier/iter; log2 softmax, per-lane l partials,
// defer-max (THR=8), diagonal-only causal mask.
// ---------------------------------------------------------------------------
__global__ __launch_bounds__(256) void attn_fwd(
    const unsigned short* __restrict__ Qr,
    const unsigned short* __restrict__ Kr,
    const unsigned short* __restrict__ Vt,
    unsigned short* __restrict__ O)
{
  __shared__ __align__(16) unsigned short Kld[2][64 * 128];
  __shared__ __align__(16) unsigned short Vld[2][128 * 64];
  __shared__ __align__(16) unsigned short Pld[4][16 * 64];

  const int tid  = threadIdx.x;
  const int lane = tid & 63;
  const int wave = tid >> 6;
  const int bx = blockIdx.x;   // 0..15
  const int h  = blockIdx.y;   // 0..31
  const int b  = blockIdx.z;   // 0..1
  const int kvh = h >> 2;
  const int lr = lane & 15;
  const int lk = (lane >> 4) * 8;
  const int orow = (lane >> 4) * 4;

  const unsigned short* Kb = Kr + (size_t)(b * KVH_ + kvh) * S_ * HD_;
  const unsigned short* Vb = Vt + (size_t)(b * KVH_ + kvh) * HD_ * S_;

  auto stage = [&](int buf, int kb) {
#pragma unroll
    for (int i = 0; i < 4; ++i) {
      const int db = i * 4096 + tid * 16;
      {  // K: 256 B/row
        const int row  = db >> 8;
        const int colb = (db & 255) ^ ((row & 7) << 4);
        cp16(Kb + (size_t)(kb * 64 + row) * HD_ + (colb >> 1),
             (char*)&Kld[buf][0] + i * 4096 + wave * 1024);
      }
      {  // V: 128 B/row
        const int row  = db >> 7;
        const int colb = (db & 127) ^ ((row & 7) << 4);
        cp16(Vb + (size_t)row * S_ + kb * 64 + (colb >> 1),
             (char*)&Vld[buf][0] + i * 4096 + wave * 1024);
      }
    }
  };

  for (int half = 0; half < 2; ++half) {
    const int qb = half ? (S_ / 64 - 1 - bx) : bx;

    const unsigned short* qbase =
        Qr + ((size_t)(b * H_ + h) * S_ + qb * 64 + wave * 16 + lr) * HD_;
    bf16x8 qf[4];
#pragma unroll
    for (int t = 0; t < 4; ++t) qf[t] = ld8(qbase + t * 32 + lk);

    f32x4 acc_o[8];
#pragma unroll
    for (int dt = 0; dt < 8; ++dt) acc_o[dt] = (f32x4){0.f, 0.f, 0.f, 0.f};
    float mrow[4], lpart[4];
#pragma unroll
    for (int r = 0; r < 4; ++r) { mrow[r] = -1e30f; lpart[r] = 0.f; }

    stage(0, 0);
    __syncthreads();

    for (int kb = 0; kb <= qb; ++kb) {
      const int cur = kb & 1;
      if (kb < qb) stage(cur ^ 1, kb + 1);   // prefetch next tile FIRST

      const char* Kc = (const char*)&Kld[cur][0];
      const char* Vc = (const char*)&Vld[cur][0];

      // S = (scale*log2e) * Q K^T  (scale folded into Q upstream)
      f32x4 accs[4];
#pragma unroll
      for (int kt = 0; kt < 4; ++kt) accs[kt] = (f32x4){0.f, 0.f, 0.f, 0.f};
      __builtin_amdgcn_s_setprio(1);
#pragma unroll
      for (int t = 0; t < 4; ++t) {
#pragma unroll
        for (int kt = 0; kt < 4; ++kt) {
          const int krow = kt * 16 + lr;
          const int kbyte = ((krow << 8) + ((t * 32 + lk) << 1)) ^ ((krow & 7) << 4);
          bf16x8 kf = ld8b(Kc, kbyte);
          accs[kt] = __builtin_amdgcn_mfma_f32_16x16x32_bf16(qf[t], kf, accs[kt], 0, 0, 0);
        }
      }
      __builtin_amdgcn_s_setprio(0);

      if (kb == qb) {  // block-uniform: mask only in the diagonal tile
#pragma unroll
        for (int r = 0; r < 4; ++r) {
          const int qg = wave * 16 + orow + r;
#pragma unroll
          for (int kt = 0; kt < 4; ++kt)
            if (kt * 16 + lr > qg) accs[kt][r] = -1e30f;
        }
      }

      // in-lane kt-max; defer-check without cross-lane reduce
      float mx[4];
#pragma unroll
      for (int r = 0; r < 4; ++r)
        mx[r] = fmaxf(fmaxf(accs[0][r], accs[1][r]), fmaxf(accs[2][r], accs[3][r]));
      int ok = (mx[0] <= mrow[0] + 8.f) && (mx[1] <= mrow[1] + 8.f) &&
               (mx[2] <= mrow[2] + 8.f) && (mx[3] <= mrow[3] + 8.f);
      if (!__all(ok)) {   // rare: running max grew; full rescale
        float corr[4];
#pragma unroll
        for (int r = 0; r < 4; ++r) {
          float m = mx[r];
#pragma unroll
          for (int msk = 8; msk >= 1; msk >>= 1) m = fmaxf(m, __shfl_xor(m, msk, 64));
          float mnew = fmaxf(mrow[r], m);
          corr[r] = exp2a(mrow[r] - mnew);
          mrow[r] = mnew;
          lpart[r] *= corr[r];
        }
#pragma unroll
        for (int dt = 0; dt < 8; ++dt)
#pragma unroll
          for (int r = 0; r < 4; ++r) acc_o[dt][r] *= corr[r];
      }

      // p = exp2(s - m); accumulate per-lane partials; store bf16 P
#pragma unroll
      for (int r = 0; r < 4; ++r) {
        const int prow = orow + r;
#pragma unroll
        for (int kt = 0; kt < 4; ++kt) {
          float p = exp2a(accs[kt][r] - mrow[r]);
          lpart[r] += p;
          const int pbyte = ((prow << 7) + ((kt * 16 + lr) << 1)) ^ ((prow & 7) << 4);
          *(__bf16*)((char*)&Pld[wave][0] + pbyte) = (__bf16)p;
        }
      }

      asm volatile("" ::: "memory");  // Pld ushort-write vs bf16x8-read (TBAA)

      // O += P V
      __builtin_amdgcn_s_setprio(1);
#pragma unroll
      for (int kc = 0; kc < 2; ++kc) {
        const int pbyte = ((lr << 7) + ((kc * 32 + lk) << 1)) ^ ((lr & 7) << 4);
        bf16x8 pf = ld8b(&Pld[wave][0], pbyte);
#pragma unroll
        for (int dt = 0; dt < 8; ++dt) {
          const int vrow = dt * 16 + lr;
          const int vbyte = ((vrow << 7) + ((kc * 32 + lk) << 1)) ^ ((vrow & 7) << 4);
          bf16x8 vf = ld8b(Vc, vbyte);
          acc_o[dt] = __builtin_amdgcn_mfma_f32_16x16x32_bf16(pf, vf, acc_o[dt], 0, 0, 0);
        }
      }
      __builtin_amdgcn_s_setprio(0);

      __syncthreads();  // lands prefetch + separates buffer reuse
    }

    // one cross-lane sum reduce at the end
#pragma unroll
    for (int r = 0; r < 4; ++r) {
      float s = lpart[r];
#pragma unroll
      for (int msk = 8; msk >= 1; msk >>= 1) s += __shfl_xor(s, msk, 64);
      float inv = 1.f / s;
      size_t rowoff =
          (size_t)(b * S_ + qb * 64 + wave * 16 + orow + r) * (H_ * HD_) + h * HD_;
#pragma unroll
      for (int dt = 0; dt < 8; ++dt)
        O[rowoff + dt * 16 + lr] = f2bf(acc_o[dt][r] * inv);
    }
  }
}

// Diagnostic: if ws_size is too small, fill fp32 output with sentinel 12345.
__global__ void fill_sentinel(float* __restrict__ O, int n) {
  int i = blockIdx.x * 256 + threadIdx.x;
  if (i < n) O[i] = 12345.0f;
}

// ---------------------------------------------------------------------------
extern "C" void kernel_launch(void* const* d_in, const int* in_sizes, int n_in,
                              void* d_out, int out_size, void* d_ws, size_t ws_size,
                              hipStream_t stream) {
  const float* hidden = (const float*)d_in[0]; // [B,S,D] fp32
  const float* wqkv   = (const float*)d_in[1]; // [6144,4096] fp32
  const float* wdense = (const float*)d_in[2]; // [4096,4096] fp32
  float* out = (float*)d_out;                  // [B,S,4096] fp32

  const size_t NEED = 134217728;
  if (ws_size < NEED) {
    fill_sentinel<<<dim3((out_size + 255) / 256), dim3(256), 0, stream>>>(out, out_size);
    return;
  }

  char* ws = (char*)d_ws;
  // Phase 1 layout
  unsigned short* Hb    = (unsigned short*)(ws);                 // 33,554,432 B
  unsigned short* Wqb   = (unsigned short*)(ws + 33554432);      // 50,331,648 B
  unsigned short* fused = (unsigned short*)(ws + 83886080);      // 50,331,648 B
  // Phase 2 layout (after GEMM1: Hb/Wqb dead; Wdb written AFTER GEMM1!)
  unsigned short* Qr    = (unsigned short*)(ws);                 // 33,554,432 B
  unsigned short* Kr    = (unsigned short*)(ws + 33554432);      //  8,388,608 B
  unsigned short* Vt    = (unsigned short*)(ws + 41943040);      //  8,388,608 B
  unsigned short* Wdb   = (unsigned short*)(ws + 50331648);      // 33,554,432 B
  unsigned short* attn_out = (unsigned short*)(ws + 83886080);   // 33,554,432 B (over fused)

  const int nH4 = B_ * S_ * D_ / 4;   // 4,194,304
  const int nQ4 = NE_ * D_ / 4;       // 6,291,456
  const int nD4 = D_ * D_ / 4;        // 4,194,304

  cvt2_f32_bf16<<<dim3((nH4 + nQ4 + 255) / 256), dim3(256), 0, stream>>>(
      hidden, Hb, nH4, wqkv, Wqb, nQ4);

  gemm256<unsigned short, 192><<<dim3(NE_ / 192, (B_ * S_) / 256), dim3(512), 0, stream>>>(
      Hb, Wqb, fused, B_ * S_, NE_);

  rope_scatter_cvt<<<dim3((ROPE_N + nD4 + 255) / 256), dim3(256), 0, stream>>>(
      fused, Qr, Kr, Vt, wdense, Wdb, nD4);

  attn_fwd<<<dim3(16, H_, B_), dim3(256), 0, stream>>>(Qr, Kr, Vt, attn_out);

  gemm256<float, 256><<<dim3(D_ / 256, (B_ * S_) / 256), dim3(512), 0, stream>>>(
      attn_out, Wdb, out, B_ * S_, D_);
}

// Round 15
// 523.308 us; speedup vs baseline: 1.0071x; 1.0071x over previous
//
#include <hip/hip_runtime.h>

#define B_   2
#define S_   2048
#define D_   4096
#define H_   32
#define KVH_ 8
#define HD_  128
#define NE_  6144   // (KVH*2+H)*HD

using f32x4  = __attribute__((ext_vector_type(4))) float;
using bf16x8 = __attribute__((ext_vector_type(8))) __bf16;
using u16x8  = __attribute__((ext_vector_type(8))) unsigned short;

__device__ __forceinline__ unsigned short f2bf(float f) {
  union { float f; unsigned u; } v; v.f = f;
  unsigned r = v.u + 0x7FFFu + ((v.u >> 16) & 1u);
  return (unsigned short)(r >> 16);
}
__device__ __forceinline__ float bf2f(unsigned short h) {
  union { unsigned u; float f; } v; v.u = ((unsigned)h) << 16; return v.f;
}
__device__ __forceinline__ bf16x8 ld8(const unsigned short* p) {
  return *reinterpret_cast<const bf16x8*>(p);
}
__device__ __forceinline__ bf16x8 ld8b(const void* base, int byte_off) {
  return *reinterpret_cast<const bf16x8*>((const char*)base + byte_off);
}
__device__ __forceinline__ void cp16(const void* g, void* l) {
  __builtin_amdgcn_global_load_lds(
      (const __attribute__((address_space(1))) void*)g,
      (__attribute__((address_space(3))) void*)l, 16, 0, 0);
}
__device__ __forceinline__ float exp2a(float x) {   // 2^x via v_exp_f32
  float r; asm("v_exp_f32 %0, %1" : "=v"(r) : "v"(x)); return r;
}

#define SC2F 0.12751652f   // (1/sqrt(128)) * log2(e)

// ---------------------------------------------------------------------------
// Two segments in one launch (dests must be disjoint!).
// ---------------------------------------------------------------------------
__global__ __launch_bounds__(256) void cvt2_f32_bf16(
    const float* __restrict__ s0, unsigned short* __restrict__ d0, int n0,
    const float* __restrict__ s1, unsigned short* __restrict__ d1, int n1)
{
  int i = blockIdx.x * 256 + threadIdx.x;
  const float* src; unsigned short* dst;
  if (i < n0) { src = s0; dst = d0; }
  else        { i -= n0; if (i >= n1) return; src = s1; dst = d1; }
  f32x4 v = *reinterpret_cast<const f32x4*>(src + (size_t)i * 4);
  ushort4 o;
  o.x = f2bf(v[0]); o.y = f2bf(v[1]); o.z = f2bf(v[2]); o.w = f2bf(v[3]);
  *reinterpret_cast<ushort4*>(dst + (size_t)i * 4) = o;
}

// ---------------------------------------------------------------------------
// 256xNT-tile 8-phase GEMM: C[M,N] = A[M,K] * B[N,K]^T, K=4096 fixed.
// r13 schedule restored (best measured: GEMM1 200us, MfmaUtil 47.8, 0 bank
// conflicts): A stages @P1/P2, B @P3/P4, counted vmcnt(NB) at P4/P8.
// r14's one-phase-earlier shift REGRESSED (204us) -- load clustering vs
// interleave; keep r13 order permanently.
// ---------------------------------------------------------------------------
template <typename OutT, int NT>
__global__ __launch_bounds__(512, 2) void gemm256(
    const unsigned short* __restrict__ A,
    const unsigned short* __restrict__ Bw,
    OutT* __restrict__ C, int M, int N)
{
  constexpr int K  = 4096;
  constexpr int NI = (K / 64) / 2;     // 32 iterations, 2 K-tiles each
  constexpr int NB = NT / 64;          // B chunks per tile (3 or 4)
  constexpr int NN = NT / 64;          // n-frags per wave
  constexpr int WN = NT / 4;           // per-wave N extent
  constexpr int BBUF = NT * 128;       // B bytes per buffer
  __shared__ __align__(16) char lds[65536 + 2 * BBUF];

  const int tid  = threadIdx.x;
  const int lane = tid & 63;
  const int wave = tid >> 6;
  const int wr = wave >> 2;            // 0..1  (M half)
  const int wc = wave & 3;             // 0..3  (N quarter)
  const int lr = lane & 15;
  const int lk = (lane >> 4) * 8;

  int id  = blockIdx.y * gridDim.x + blockIdx.x;
  const int nwg = gridDim.x * gridDim.y;
  if ((nwg & 7) == 0) { const int q = nwg >> 3; id = (id & 7) * q + (id >> 3); }
  const int row0 = (id / gridDim.x) * 256;
  const int col0 = (id % gridDim.x) * NT;

  // A staging: 2 halves x 2 loads/thread (16KB each).
  int rwA[2], csA[2], dbA[2];
#pragma unroll
  for (int j = 0; j < 2; ++j) {
    dbA[j] = j * 8192 + tid * 16;
    rwA[j] = dbA[j] >> 7;
    csA[j] = ((dbA[j] & 127) ^ ((rwA[j] & 7) << 4)) >> 1;
  }
  auto stA = [&](int buf, int h, int t) {
#pragma unroll
    for (int j = 0; j < 2; ++j)
      cp16(A + (size_t)(row0 + h * 128 + rwA[j]) * K + t * 64 + csA[j],
           lds + buf * 32768 + h * 16384 + dbA[j]);
  };
  // B staging: NB chunks x 1 load/thread (8KB each, 64 rows).
  const int dbB = tid * 16;
  const int rwB = dbB >> 7;                              // 0..63
  const int csB = ((dbB & 127) ^ ((rwB & 7) << 4)) >> 1; // chunk row base %8==0
  auto stB = [&](int buf, int c, int t) {
    cp16(Bw + (size_t)(col0 + c * 64 + rwB) * K + t * 64 + csB,
         lds + 65536 + buf * BBUF + c * 8192 + dbB);
  };

  const int cb0 = ((0 + lk) << 1) ^ ((lr & 7) << 4);
  const int cb1 = ((32 + lk) << 1) ^ ((lr & 7) << 4);
  const int aRowB = (wr * 128 + lr) * 128;
  const int bRowB = (wc * WN + lr) * 128;

  f32x4 acc[8][NN];
#pragma unroll
  for (int m = 0; m < 8; ++m)
#pragma unroll
    for (int n = 0; n < NN; ++n) acc[m][n] = (f32x4){0.f, 0.f, 0.f, 0.f};
  bf16x8 bfr[NN][2];

#define FENCE asm volatile("" ::: "memory")
#define VMNB  do { if constexpr (NB == 4) asm volatile("s_waitcnt vmcnt(4)" ::: "memory"); \
                   else                   asm volatile("s_waitcnt vmcnt(3)" ::: "memory"); } while (0)
#define VM0   asm volatile("s_waitcnt vmcnt(0)" ::: "memory")

#define PHASE(p, buf, STAGE, WAIT)                                             \
  {                                                                            \
    if ((p) == 0) {                                                            \
      _Pragma("unroll")                                                        \
      for (int n = 0; n < NN; ++n) {                                           \
        bfr[n][0] = ld8b(lds, 65536 + (buf) * BBUF + bRowB + n * 2048 + cb0);  \
        bfr[n][1] = ld8b(lds, 65536 + (buf) * BBUF + bRowB + n * 2048 + cb1);  \
      }                                                                        \
    }                                                                          \
    bf16x8 a00 = ld8b(lds, (buf) * 32768 + aRowB + ((p) * 2 + 0) * 2048 + cb0);\
    bf16x8 a01 = ld8b(lds, (buf) * 32768 + aRowB + ((p) * 2 + 0) * 2048 + cb1);\
    bf16x8 a10 = ld8b(lds, (buf) * 32768 + aRowB + ((p) * 2 + 1) * 2048 + cb0);\
    bf16x8 a11 = ld8b(lds, (buf) * 32768 + aRowB + ((p) * 2 + 1) * 2048 + cb1);\
    STAGE;                                                                     \
    FENCE;                                                                     \
    __builtin_amdgcn_s_barrier();                                              \
    __builtin_amdgcn_s_setprio(1);                                             \
    _Pragma("unroll")                                                          \
    for (int n = 0; n < NN; ++n) {                                             \
      acc[(p)*2+0][n] = __builtin_amdgcn_mfma_f32_16x16x32_bf16(a00, bfr[n][0], acc[(p)*2+0][n], 0, 0, 0); \
      acc[(p)*2+0][n] = __builtin_amdgcn_mfma_f32_16x16x32_bf16(a01, bfr[n][1], acc[(p)*2+0][n], 0, 0, 0); \
      acc[(p)*2+1][n] = __builtin_amdgcn_mfma_f32_16x16x32_bf16(a10, bfr[n][0], acc[(p)*2+1][n], 0, 0, 0); \
      acc[(p)*2+1][n] = __builtin_amdgcn_mfma_f32_16x16x32_bf16(a11, bfr[n][1], acc[(p)*2+1][n], 0, 0, 0); \
    }                                                                          \
    __builtin_amdgcn_s_setprio(0);                                             \
    WAIT;                                                                      \
    FENCE;                                                                     \
    __builtin_amdgcn_s_barrier();                                              \
  }

  // Prologue: tile0 B+A into buf0, tile1 B into buf1; allow tile1-B in flight.
#pragma unroll
  for (int c = 0; c < NB; ++c) stB(0, c, 0);
  stA(0, 0, 0); stA(0, 1, 0);
#pragma unroll
  for (int c = 0; c < NB; ++c) stB(1, c, 1);
  VMNB;
  FENCE;
  __builtin_amdgcn_s_barrier();

  for (int i = 0; i < NI; ++i) {
    const int t1  = 2 * i + 1;
    const int tn0 = 2 * i + 2;
    const int tn1 = 2 * i + 3;
    const bool pre = (i + 1 < NI);
    // K-tile 2i in buf0
    PHASE(0, 0, { stA(1, 0, t1); }, {});
    PHASE(1, 0, { stA(1, 1, t1); }, {});
    PHASE(2, 0, { if (pre) { stB(0, 0, tn0); stB(0, 1, tn0); } }, {});
    PHASE(3, 0, { if (pre) { _Pragma("unroll") for (int c = 2; c < NB; ++c) stB(0, c, tn0); } },
          { if (pre) { VMNB; } else { VM0; } });
    // K-tile 2i+1 in buf1
    PHASE(0, 1, { if (pre) stA(0, 0, tn0); }, {});
    PHASE(1, 1, { if (pre) stA(0, 1, tn0); }, {});
    PHASE(2, 1, { if (pre) { stB(1, 0, tn1); stB(1, 1, tn1); } }, {});
    PHASE(3, 1, { if (pre) { _Pragma("unroll") for (int c = 2; c < NB; ++c) stB(1, c, tn1); } },
          { if (pre) { VMNB; } });
  }
#undef PHASE
#undef FENCE
#undef VMNB
#undef VM0

  const int orow = (lane >> 4) * 4;
#pragma unroll
  for (int m = 0; m < 8; ++m) {
    const int gr0 = row0 + wr * 128 + m * 16 + orow;
#pragma unroll
    for (int n = 0; n < NN; ++n) {
      const int gc = col0 + wc * WN + n * 16 + lr;
#pragma unroll
      for (int r = 0; r < 4; ++r) {
        float val = acc[m][n][r];
        if constexpr (sizeof(OutT) == 2)
          C[(size_t)(gr0 + r) * N + gc] = f2bf(val);
        else
          C[(size_t)(gr0 + r) * N + gc] = val;
      }
    }
  }
}

// ---------------------------------------------------------------------------
// Fused: (a) rope_scatter of fused[B,S,48,128] -> Qr (rope, pre-scaled by
// SC2 = scale*log2e), Kr (rope), Vt (transposed); (b) wdense fp32->bf16 cvt.
// Both run after GEMM1; disjoint outputs -> safe in one launch.
// ---------------------------------------------------------------------------
#define ROPE_N (B_ * S_ * 48 * 8)
__global__ __launch_bounds__(256) void rope_scatter_cvt(
    const unsigned short* __restrict__ fused,
    unsigned short* __restrict__ Qr,
    unsigned short* __restrict__ Kr,
    unsigned short* __restrict__ Vt,
    const float* __restrict__ wdense,
    unsigned short* __restrict__ Wdb,
    int nD4)
{
  int idx = blockIdx.x * 256 + threadIdx.x;
  if (idx >= ROPE_N) {   // wdense conversion range
    int i = idx - ROPE_N;
    if (i >= nD4) return;
    f32x4 v = *reinterpret_cast<const f32x4*>(wdense + (size_t)i * 4);
    ushort4 o;
    o.x = f2bf(v[0]); o.y = f2bf(v[1]); o.z = f2bf(v[2]); o.w = f2bf(v[3]);
    *reinterpret_cast<ushort4*>(Wdb + (size_t)i * 4) = o;
    return;
  }
  int dg = idx & 7;            // d = dg*8 + jj
  int t = idx >> 3;
  int e = t % 48;
  int bs = t / 48;
  int s = bs % S_;
  int b = bs / S_;
  int kvh = e / 6, j = e % 6;
  const unsigned short* src = fused + (size_t)bs * NE_ + e * 128 + dg * 8;
  u16x8 lo = *reinterpret_cast<const u16x8*>(src);
  u16x8 hi = *reinterpret_cast<const u16x8*>(src + 64);
  if (j == 5) {  // V: transposed store
    size_t base = (size_t)(b * KVH_ + kvh) * HD_ * S_ + s;
#pragma unroll
    for (int jj = 0; jj < 8; ++jj) {
      Vt[base + (size_t)(dg * 8 + jj) * S_]      = lo[jj];
      Vt[base + (size_t)(dg * 8 + jj + 64) * S_] = hi[jj];
    }
  } else {
    const float sc = (j == 4) ? 1.0f : SC2F;   // Q heads pre-scaled
    u16x8 olo, ohi;
#pragma unroll
    for (int jj = 0; jj < 8; ++jj) {
      int d = dg * 8 + jj;
      float x1 = bf2f(lo[jj]), x2 = bf2f(hi[jj]);
      float inv = __expf(-(float)d * (9.2103403719761836f / 64.0f));
      float ang = (float)s * inv;
      float sn, c;
      sincosf(ang, &sn, &c);
      olo[jj] = f2bf((x1 * c - x2 * sn) * sc);
      ohi[jj] = f2bf((x2 * c + x1 * sn) * sc);
    }
    unsigned short* dst;
    if (j == 4) dst = Kr + ((size_t)(b * KVH_ + kvh) * S_ + s) * HD_;
    else        dst = Qr + ((size_t)(b * H_ + kvh * 4 + j) * S_ + s) * HD_;
    *reinterpret_cast<u16x8*>(dst + dg * 8)      = olo;
    *reinterpret_cast<u16x8*>(dst + dg * 8 + 64) = ohi;
  }
}

// ---------------------------------------------------------------------------
// Causal GQA flash attention (round-10/13 structure, Q pre-scaled upstream):
// QBLK=64 (4 waves x 16 q-rows), K/V dbuf (72 KB -> 2 blocks/CU),
// prefetch-first, one barrier/iter; log2 softmax, per-lane l partials,
// defer-max (THR=8), diagonal-only causal mask.
// ---------------------------------------------------------------------------
__global__ __launch_bounds__(256) void attn_fwd(
    const unsigned short* __restrict__ Qr,
    const unsigned short* __restrict__ Kr,
    const unsigned short* __restrict__ Vt,
    unsigned short* __restrict__ O)
{
  __shared__ __align__(16) unsigned short Kld[2][64 * 128];
  __shared__ __align__(16) unsigned short Vld[2][128 * 64];
  __shared__ __align__(16) unsigned short Pld[4][16 * 64];

  const int tid  = threadIdx.x;
  const int lane = tid & 63;
  const int wave = tid >> 6;
  const int bx = blockIdx.x;   // 0..15
  const int h  = blockIdx.y;   // 0..31
  const int b  = blockIdx.z;   // 0..1
  const int kvh = h >> 2;
  const int lr = lane & 15;
  const int lk = (lane >> 4) * 8;
  const int orow = (lane >> 4) * 4;

  const unsigned short* Kb = Kr + (size_t)(b * KVH_ + kvh) * S_ * HD_;
  const unsigned short* Vb = Vt + (size_t)(b * KVH_ + kvh) * HD_ * S_;

  auto stage = [&](int buf, int kb) {
#pragma unroll
    for (int i = 0; i < 4; ++i) {
      const int db = i * 4096 + tid * 16;
      {  // K: 256 B/row
        const int row  = db >> 8;
        const int colb = (db & 255) ^ ((row & 7) << 4);
        cp16(Kb + (size_t)(kb * 64 + row) * HD_ + (colb >> 1),
             (char*)&Kld[buf][0] + i * 4096 + wave * 1024);
      }
      {  // V: 128 B/row
        const int row  = db >> 7;
        const int colb = (db & 127) ^ ((row & 7) << 4);
        cp16(Vb + (size_t)row * S_ + kb * 64 + (colb >> 1),
             (char*)&Vld[buf][0] + i * 4096 + wave * 1024);
      }
    }
  };

  for (int half = 0; half < 2; ++half) {
    const int qb = half ? (S_ / 64 - 1 - bx) : bx;

    const unsigned short* qbase =
        Qr + ((size_t)(b * H_ + h) * S_ + qb * 64 + wave * 16 + lr) * HD_;
    bf16x8 qf[4];
#pragma unroll
    for (int t = 0; t < 4; ++t) qf[t] = ld8(qbase + t * 32 + lk);

    f32x4 acc_o[8];
#pragma unroll
    for (int dt = 0; dt < 8; ++dt) acc_o[dt] = (f32x4){0.f, 0.f, 0.f, 0.f};
    float mrow[4], lpart[4];
#pragma unroll
    for (int r = 0; r < 4; ++r) { mrow[r] = -1e30f; lpart[r] = 0.f; }

    stage(0, 0);
    __syncthreads();

    for (int kb = 0; kb <= qb; ++kb) {
      const int cur = kb & 1;
      if (kb < qb) stage(cur ^ 1, kb + 1);   // prefetch next tile FIRST

      const char* Kc = (const char*)&Kld[cur][0];
      const char* Vc = (const char*)&Vld[cur][0];

      // S = (scale*log2e) * Q K^T  (scale folded into Q upstream)
      f32x4 accs[4];
#pragma unroll
      for (int kt = 0; kt < 4; ++kt) accs[kt] = (f32x4){0.f, 0.f, 0.f, 0.f};
      __builtin_amdgcn_s_setprio(1);
#pragma unroll
      for (int t = 0; t < 4; ++t) {
#pragma unroll
        for (int kt = 0; kt < 4; ++kt) {
          const int krow = kt * 16 + lr;
          const int kbyte = ((krow << 8) + ((t * 32 + lk) << 1)) ^ ((krow & 7) << 4);
          bf16x8 kf = ld8b(Kc, kbyte);
          accs[kt] = __builtin_amdgcn_mfma_f32_16x16x32_bf16(qf[t], kf, accs[kt], 0, 0, 0);
        }
      }
      __builtin_amdgcn_s_setprio(0);

      if (kb == qb) {  // block-uniform: mask only in the diagonal tile
#pragma unroll
        for (int r = 0; r < 4; ++r) {
          const int qg = wave * 16 + orow + r;
#pragma unroll
          for (int kt = 0; kt < 4; ++kt)
            if (kt * 16 + lr > qg) accs[kt][r] = -1e30f;
        }
      }

      // in-lane kt-max; defer-check without cross-lane reduce
      float mx[4];
#pragma unroll
      for (int r = 0; r < 4; ++r)
        mx[r] = fmaxf(fmaxf(accs[0][r], accs[1][r]), fmaxf(accs[2][r], accs[3][r]));
      int ok = (mx[0] <= mrow[0] + 8.f) && (mx[1] <= mrow[1] + 8.f) &&
               (mx[2] <= mrow[2] + 8.f) && (mx[3] <= mrow[3] + 8.f);
      if (!__all(ok)) {   // rare: running max grew; full rescale
        float corr[4];
#pragma unroll
        for (int r = 0; r < 4; ++r) {
          float m = mx[r];
#pragma unroll
          for (int msk = 8; msk >= 1; msk >>= 1) m = fmaxf(m, __shfl_xor(m, msk, 64));
          float mnew = fmaxf(mrow[r], m);
          corr[r] = exp2a(mrow[r] - mnew);
          mrow[r] = mnew;
          lpart[r] *= corr[r];
        }
#pragma unroll
        for (int dt = 0; dt < 8; ++dt)
#pragma unroll
          for (int r = 0; r < 4; ++r) acc_o[dt][r] *= corr[r];
      }

      // p = exp2(s - m); accumulate per-lane partials; store bf16 P
#pragma unroll
      for (int r = 0; r < 4; ++r) {
        const int prow = orow + r;
#pragma unroll
        for (int kt = 0; kt < 4; ++kt) {
          float p = exp2a(accs[kt][r] - mrow[r]);
          lpart[r] += p;
          const int pbyte = ((prow << 7) + ((kt * 16 + lr) << 1)) ^ ((prow & 7) << 4);
          *(__bf16*)((char*)&Pld[wave][0] + pbyte) = (__bf16)p;
        }
      }

      asm volatile("" ::: "memory");  // Pld ushort-write vs bf16x8-read (TBAA)

      // O += P V
      __builtin_amdgcn_s_setprio(1);
#pragma unroll
      for (int kc = 0; kc < 2; ++kc) {
        const int pbyte = ((lr << 7) + ((kc * 32 + lk) << 1)) ^ ((lr & 7) << 4);
        bf16x8 pf = ld8b(&Pld[wave][0], pbyte);
#pragma unroll
        for (int dt = 0; dt < 8; ++dt) {
          const int vrow = dt * 16 + lr;
          const int vbyte = ((vrow << 7) + ((kc * 32 + lk) << 1)) ^ ((vrow & 7) << 4);
          bf16x8 vf = ld8b(Vc, vbyte);
          acc_o[dt] = __builtin_amdgcn_mfma_f32_16x16x32_bf16(pf, vf, acc_o[dt], 0, 0, 0);
        }
      }
      __builtin_amdgcn_s_setprio(0);

      __syncthreads();  // lands prefetch + separates buffer reuse
    }

    // one cross-lane sum reduce at the end
#pragma unroll
    for (int r = 0; r < 4; ++r) {
      float s = lpart[r];
#pragma unroll
      for (int msk = 8; msk >= 1; msk >>= 1) s += __shfl_xor(s, msk, 64);
      float inv = 1.f / s;
      size_t rowoff =
          (size_t)(b * S_ + qb * 64 + wave * 16 + orow + r) * (H_ * HD_) + h * HD_;
#pragma unroll
      for (int dt = 0; dt < 8; ++dt)
        O[rowoff + dt * 16 + lr] = f2bf(acc_o[dt][r] * inv);
    }
  }
}

// Diagnostic: if ws_size is too small, fill fp32 output with sentinel 12345.
__global__ void fill_sentinel(float* __restrict__ O, int n) {
  int i = blockIdx.x * 256 + threadIdx.x;
  if (i < n) O[i] = 12345.0f;
}

// ---------------------------------------------------------------------------
extern "C" void kernel_launch(void* const* d_in, const int* in_sizes, int n_in,
                              void* d_out, int out_size, void* d_ws, size_t ws_size,
                              hipStream_t stream) {
  const float* hidden = (const float*)d_in[0]; // [B,S,D] fp32
  const float* wqkv   = (const float*)d_in[1]; // [6144,4096] fp32
  const float* wdense = (const float*)d_in[2]; // [4096,4096] fp32
  float* out = (float*)d_out;                  // [B,S,4096] fp32

  const size_t NEED = 134217728;
  if (ws_size < NEED) {
    fill_sentinel<<<dim3((out_size + 255) / 256), dim3(256), 0, stream>>>(out, out_size);
    return;
  }

  char* ws = (char*)d_ws;
  // Phase 1 layout
  unsigned short* Hb    = (unsigned short*)(ws);                 // 33,554,432 B
  unsigned short* Wqb   = (unsigned short*)(ws + 33554432);      // 50,331,648 B
  unsigned short* fused = (unsigned short*)(ws + 83886080);      // 50,331,648 B
  // Phase 2 layout (after GEMM1: Hb/Wqb dead; Wdb written AFTER GEMM1!)
  unsigned short* Qr    = (unsigned short*)(ws);                 // 33,554,432 B
  unsigned short* Kr    = (unsigned short*)(ws + 33554432);      //  8,388,608 B
  unsigned short* Vt    = (unsigned short*)(ws + 41943040);      //  8,388,608 B
  unsigned short* Wdb   = (unsigned short*)(ws + 50331648);      // 33,554,432 B
  unsigned short* attn_out = (unsigned short*)(ws + 83886080);   // 33,554,432 B (over fused)

  const int nH4 = B_ * S_ * D_ / 4;   // 4,194,304
  const int nQ4 = NE_ * D_ / 4;       // 6,291,456
  const int nD4 = D_ * D_ / 4;        // 4,194,304

  cvt2_f32_bf16<<<dim3((nH4 + nQ4 + 255) / 256), dim3(256), 0, stream>>>(
      hidden, Hb, nH4, wqkv, Wqb, nQ4);

  gemm256<unsigned short, 192><<<dim3(NE_ / 192, (B_ * S_) / 256), dim3(512), 0, stream>>>(
      Hb, Wqb, fused, B_ * S_, NE_);

  rope_scatter_cvt<<<dim3((ROPE_N + nD4 + 255) / 256), dim3(256), 0, stream>>>(
      fused, Qr, Kr, Vt, wdense, Wdb, nD4);

  attn_fwd<<<dim3(16, H_, B_), dim3(256), 0, stream>>>(Qr, Kr, Vt, attn_out);

  gemm256<float, 256><<<dim3(D_ / 256, (B_ * S_) / 256), dim3(512), 0, stream>>>(
      attn_out, Wdb, out, B_ * S_, D_);
}

// Round 16
// 474.501 us; speedup vs baseline: 1.1107x; 1.1029x over previous
//
#include <hip/hip_runtime.h>

#define B_   2
#define S_   2048
#define D_   4096
#define H_   32
#define KVH_ 8
#define HD_  128
#define NE_  6144   // (KVH*2+H)*HD

using f32x4  = __attribute__((ext_vector_type(4))) float;
using f32x16 = __attribute__((ext_vector_type(16))) float;
using bf16x8 = __attribute__((ext_vector_type(8))) __bf16;
using u16x8  = __attribute__((ext_vector_type(8))) unsigned short;

__device__ __forceinline__ unsigned short f2bf(float f) {
  union { float f; unsigned u; } v; v.f = f;
  unsigned r = v.u + 0x7FFFu + ((v.u >> 16) & 1u);
  return (unsigned short)(r >> 16);
}
__device__ __forceinline__ float bf2f(unsigned short h) {
  union { unsigned u; float f; } v; v.u = ((unsigned)h) << 16; return v.f;
}
__device__ __forceinline__ bf16x8 ld8(const unsigned short* p) {
  return *reinterpret_cast<const bf16x8*>(p);
}
__device__ __forceinline__ bf16x8 ld8b(const void* base, int byte_off) {
  return *reinterpret_cast<const bf16x8*>((const char*)base + byte_off);
}
__device__ __forceinline__ void cp16(const void* g, void* l) {
  __builtin_amdgcn_global_load_lds(
      (const __attribute__((address_space(1))) void*)g,
      (__attribute__((address_space(3))) void*)l, 16, 0, 0);
}
__device__ __forceinline__ float exp2a(float x) {   // 2^x via v_exp_f32
  float r; asm("v_exp_f32 %0, %1" : "=v"(r) : "v"(x)); return r;
}
__device__ __forceinline__ unsigned cvtpk(float lo, float hi) { // 2xf32 -> 2xbf16
  unsigned r; asm("v_cvt_pk_bf16_f32 %0, %1, %2" : "=v"(r) : "v"(lo), "v"(hi));
  return r;
}

#define SC2F 0.12751652f   // (1/sqrt(128)) * log2(e)

// ---------------------------------------------------------------------------
// Two segments in one launch (dests must be disjoint!).
// ---------------------------------------------------------------------------
__global__ __launch_bounds__(256) void cvt2_f32_bf16(
    const float* __restrict__ s0, unsigned short* __restrict__ d0, int n0,
    const float* __restrict__ s1, unsigned short* __restrict__ d1, int n1)
{
  int i = blockIdx.x * 256 + threadIdx.x;
  const float* src; unsigned short* dst;
  if (i < n0) { src = s0; dst = d0; }
  else        { i -= n0; if (i >= n1) return; src = s1; dst = d1; }
  f32x4 v = *reinterpret_cast<const f32x4*>(src + (size_t)i * 4);
  ushort4 o;
  o.x = f2bf(v[0]); o.y = f2bf(v[1]); o.z = f2bf(v[2]); o.w = f2bf(v[3]);
  *reinterpret_cast<ushort4*>(dst + (size_t)i * 4) = o;
}

// ---------------------------------------------------------------------------
// 256xNT-tile 8-phase GEMM (r13/r15 schedule — frozen).
// ---------------------------------------------------------------------------
template <typename OutT, int NT>
__global__ __launch_bounds__(512, 2) void gemm256(
    const unsigned short* __restrict__ A,
    const unsigned short* __restrict__ Bw,
    OutT* __restrict__ C, int M, int N)
{
  constexpr int K  = 4096;
  constexpr int NI = (K / 64) / 2;
  constexpr int NB = NT / 64;
  constexpr int NN = NT / 64;
  constexpr int WN = NT / 4;
  constexpr int BBUF = NT * 128;
  __shared__ __align__(16) char lds[65536 + 2 * BBUF];

  const int tid  = threadIdx.x;
  const int lane = tid & 63;
  const int wave = tid >> 6;
  const int wr = wave >> 2;
  const int wc = wave & 3;
  const int lr = lane & 15;
  const int lk = (lane >> 4) * 8;

  int id  = blockIdx.y * gridDim.x + blockIdx.x;
  const int nwg = gridDim.x * gridDim.y;
  if ((nwg & 7) == 0) { const int q = nwg >> 3; id = (id & 7) * q + (id >> 3); }
  const int row0 = (id / gridDim.x) * 256;
  const int col0 = (id % gridDim.x) * NT;

  int rwA[2], csA[2], dbA[2];
#pragma unroll
  for (int j = 0; j < 2; ++j) {
    dbA[j] = j * 8192 + tid * 16;
    rwA[j] = dbA[j] >> 7;
    csA[j] = ((dbA[j] & 127) ^ ((rwA[j] & 7) << 4)) >> 1;
  }
  auto stA = [&](int buf, int h, int t) {
#pragma unroll
    for (int j = 0; j < 2; ++j)
      cp16(A + (size_t)(row0 + h * 128 + rwA[j]) * K + t * 64 + csA[j],
           lds + buf * 32768 + h * 16384 + dbA[j]);
  };
  const int dbB = tid * 16;
  const int rwB = dbB >> 7;
  const int csB = ((dbB & 127) ^ ((rwB & 7) << 4)) >> 1;
  auto stB = [&](int buf, int c, int t) {
    cp16(Bw + (size_t)(col0 + c * 64 + rwB) * K + t * 64 + csB,
         lds + 65536 + buf * BBUF + c * 8192 + dbB);
  };

  const int cb0 = ((0 + lk) << 1) ^ ((lr & 7) << 4);
  const int cb1 = ((32 + lk) << 1) ^ ((lr & 7) << 4);
  const int aRowB = (wr * 128 + lr) * 128;
  const int bRowB = (wc * WN + lr) * 128;

  f32x4 acc[8][NN];
#pragma unroll
  for (int m = 0; m < 8; ++m)
#pragma unroll
    for (int n = 0; n < NN; ++n) acc[m][n] = (f32x4){0.f, 0.f, 0.f, 0.f};
  bf16x8 bfr[NN][2];

#define FENCE asm volatile("" ::: "memory")
#define VMNB  do { if constexpr (NB == 4) asm volatile("s_waitcnt vmcnt(4)" ::: "memory"); \
                   else                   asm volatile("s_waitcnt vmcnt(3)" ::: "memory"); } while (0)
#define VM0   asm volatile("s_waitcnt vmcnt(0)" ::: "memory")

#define PHASE(p, buf, STAGE, WAIT)                                             \
  {                                                                            \
    if ((p) == 0) {                                                            \
      _Pragma("unroll")                                                        \
      for (int n = 0; n < NN; ++n) {                                           \
        bfr[n][0] = ld8b(lds, 65536 + (buf) * BBUF + bRowB + n * 2048 + cb0);  \
        bfr[n][1] = ld8b(lds, 65536 + (buf) * BBUF + bRowB + n * 2048 + cb1);  \
      }                                                                        \
    }                                                                          \
    bf16x8 a00 = ld8b(lds, (buf) * 32768 + aRowB + ((p) * 2 + 0) * 2048 + cb0);\
    bf16x8 a01 = ld8b(lds, (buf) * 32768 + aRowB + ((p) * 2 + 0) * 2048 + cb1);\
    bf16x8 a10 = ld8b(lds, (buf) * 32768 + aRowB + ((p) * 2 + 1) * 2048 + cb0);\
    bf16x8 a11 = ld8b(lds, (buf) * 32768 + aRowB + ((p) * 2 + 1) * 2048 + cb1);\
    STAGE;                                                                     \
    FENCE;                                                                     \
    __builtin_amdgcn_s_barrier();                                              \
    __builtin_amdgcn_s_setprio(1);                                             \
    _Pragma("unroll")                                                          \
    for (int n = 0; n < NN; ++n) {                                             \
      acc[(p)*2+0][n] = __builtin_amdgcn_mfma_f32_16x16x32_bf16(a00, bfr[n][0], acc[(p)*2+0][n], 0, 0, 0); \
      acc[(p)*2+0][n] = __builtin_amdgcn_mfma_f32_16x16x32_bf16(a01, bfr[n][1], acc[(p)*2+0][n], 0, 0, 0); \
      acc[(p)*2+1][n] = __builtin_amdgcn_mfma_f32_16x16x32_bf16(a10, bfr[n][0], acc[(p)*2+1][n], 0, 0, 0); \
      acc[(p)*2+1][n] = __builtin_amdgcn_mfma_f32_16x16x32_bf16(a11, bfr[n][1], acc[(p)*2+1][n], 0, 0, 0); \
    }                                                                          \
    __builtin_amdgcn_s_setprio(0);                                             \
    WAIT;                                                                      \
    FENCE;                                                                     \
    __builtin_amdgcn_s_barrier();                                              \
  }

#pragma unroll
  for (int c = 0; c < NB; ++c) stB(0, c, 0);
  stA(0, 0, 0); stA(0, 1, 0);
#pragma unroll
  for (int c = 0; c < NB; ++c) stB(1, c, 1);
  VMNB;
  FENCE;
  __builtin_amdgcn_s_barrier();

  for (int i = 0; i < NI; ++i) {
    const int t1  = 2 * i + 1;
    const int tn0 = 2 * i + 2;
    const int tn1 = 2 * i + 3;
    const bool pre = (i + 1 < NI);
    PHASE(0, 0, { stA(1, 0, t1); }, {});
    PHASE(1, 0, { stA(1, 1, t1); }, {});
    PHASE(2, 0, { if (pre) { stB(0, 0, tn0); stB(0, 1, tn0); } }, {});
    PHASE(3, 0, { if (pre) { _Pragma("unroll") for (int c = 2; c < NB; ++c) stB(0, c, tn0); } },
          { if (pre) { VMNB; } else { VM0; } });
    PHASE(0, 1, { if (pre) stA(0, 0, tn0); }, {});
    PHASE(1, 1, { if (pre) stA(0, 1, tn0); }, {});
    PHASE(2, 1, { if (pre) { stB(1, 0, tn1); stB(1, 1, tn1); } }, {});
    PHASE(3, 1, { if (pre) { _Pragma("unroll") for (int c = 2; c < NB; ++c) stB(1, c, tn1); } },
          { if (pre) { VMNB; } });
  }
#undef PHASE
#undef FENCE
#undef VMNB
#undef VM0

  const int orow = (lane >> 4) * 4;
#pragma unroll
  for (int m = 0; m < 8; ++m) {
    const int gr0 = row0 + wr * 128 + m * 16 + orow;
#pragma unroll
    for (int n = 0; n < NN; ++n) {
      const int gc = col0 + wc * WN + n * 16 + lr;
#pragma unroll
      for (int r = 0; r < 4; ++r) {
        float val = acc[m][n][r];
        if constexpr (sizeof(OutT) == 2)
          C[(size_t)(gr0 + r) * N + gc] = f2bf(val);
        else
          C[(size_t)(gr0 + r) * N + gc] = val;
      }
    }
  }
}

// ---------------------------------------------------------------------------
// Fused rope_scatter + wdense cvt (r14/r15, frozen).
// ---------------------------------------------------------------------------
#define ROPE_N (B_ * S_ * 48 * 8)
__global__ __launch_bounds__(256) void rope_scatter_cvt(
    const unsigned short* __restrict__ fused,
    unsigned short* __restrict__ Qr,
    unsigned short* __restrict__ Kr,
    unsigned short* __restrict__ Vt,
    const float* __restrict__ wdense,
    unsigned short* __restrict__ Wdb,
    int nD4)
{
  int idx = blockIdx.x * 256 + threadIdx.x;
  if (idx >= ROPE_N) {
    int i = idx - ROPE_N;
    if (i >= nD4) return;
    f32x4 v = *reinterpret_cast<const f32x4*>(wdense + (size_t)i * 4);
    ushort4 o;
    o.x = f2bf(v[0]); o.y = f2bf(v[1]); o.z = f2bf(v[2]); o.w = f2bf(v[3]);
    *reinterpret_cast<ushort4*>(Wdb + (size_t)i * 4) = o;
    return;
  }
  int dg = idx & 7;
  int t = idx >> 3;
  int e = t % 48;
  int bs = t / 48;
  int s = bs % S_;
  int b = bs / S_;
  int kvh = e / 6, j = e % 6;
  const unsigned short* src = fused + (size_t)bs * NE_ + e * 128 + dg * 8;
  u16x8 lo = *reinterpret_cast<const u16x8*>(src);
  u16x8 hi = *reinterpret_cast<const u16x8*>(src + 64);
  if (j == 5) {
    size_t base = (size_t)(b * KVH_ + kvh) * HD_ * S_ + s;
#pragma unroll
    for (int jj = 0; jj < 8; ++jj) {
      Vt[base + (size_t)(dg * 8 + jj) * S_]      = lo[jj];
      Vt[base + (size_t)(dg * 8 + jj + 64) * S_] = hi[jj];
    }
  } else {
    const float sc = (j == 4) ? 1.0f : SC2F;
    u16x8 olo, ohi;
#pragma unroll
    for (int jj = 0; jj < 8; ++jj) {
      int d = dg * 8 + jj;
      float x1 = bf2f(lo[jj]), x2 = bf2f(hi[jj]);
      float inv = __expf(-(float)d * (9.2103403719761836f / 64.0f));
      float ang = (float)s * inv;
      float sn, c;
      sincosf(ang, &sn, &c);
      olo[jj] = f2bf((x1 * c - x2 * sn) * sc);
      ohi[jj] = f2bf((x2 * c + x1 * sn) * sc);
    }
    unsigned short* dst;
    if (j == 4) dst = Kr + ((size_t)(b * KVH_ + kvh) * S_ + s) * HD_;
    else        dst = Qr + ((size_t)(b * H_ + kvh * 4 + j) * S_ + s) * HD_;
    *reinterpret_cast<u16x8*>(dst + dg * 8)      = olo;
    *reinterpret_cast<u16x8*>(dst + dg * 8 + 64) = ohi;
  }
}

// ---------------------------------------------------------------------------
// Causal GQA flash attention — 32x32 swapped-QK^T, in-register softmax (T12).
// 4 waves x 32 q-rows (QBLK=128/block); KVBLK=64; K/V dbuf 64 KB, 2 blk/CU.
// QK^T: mfma(A=K, B=Q) -> lane holds S^T[k][q=lane&31] (16 regs x 2 kt).
// P -> PV A-frag fully in-register: v_cvt_pk_bf16_f32 pairs + permlane32_swap
// (frag words [w01,w23,w45,w67] after swap(w01,w45), swap(w23,w67)).
// V consumed as B-operand directly from Vt layout. No P LDS roundtrip.
// Per-lane row softmax: no butterflies in common path; defer-max (THR=8 log2).
// K-read swizzle upgraded to (row&15)<<4 (256B rows -> conflict-free).
// ---------------------------------------------------------------------------
__global__ __launch_bounds__(256, 2) void attn_fwd(
    const unsigned short* __restrict__ Qr,
    const unsigned short* __restrict__ Kr,
    const unsigned short* __restrict__ Vt,
    unsigned short* __restrict__ O)
{
  __shared__ __align__(16) unsigned short Kld[2][64 * 128];
  __shared__ __align__(16) unsigned short Vld[2][128 * 64];

  const int tid  = threadIdx.x;
  const int lane = tid & 63;
  const int wave = tid >> 6;     // 0..3
  const int bx = blockIdx.x;     // 0..7
  const int hh = blockIdx.y;     // 0..31
  const int b  = blockIdx.z;     // 0..1
  const int kvh = hh >> 2;
  const int q31 = lane & 31;
  const int h   = lane >> 5;     // 0/1

  const unsigned short* Kb = Kr + (size_t)(b * KVH_ + kvh) * S_ * HD_;
  const unsigned short* Vb = Vt + (size_t)(b * KVH_ + kvh) * HD_ * S_;

  // K: rows 256B, swizzle (row&15)<<4 (inverse-swizzled global source).
  // V: rows 128B, swizzle (row&7)<<4 (unchanged).
  auto stage = [&](int buf, int kb) {
#pragma unroll
    for (int i = 0; i < 4; ++i) {
      const int db = i * 4096 + tid * 16;
      {  // K
        const int row  = db >> 8;
        const int colb = (db & 255) ^ ((row & 15) << 4);
        cp16(Kb + (size_t)(kb * 64 + row) * HD_ + (colb >> 1),
             (char*)&Kld[buf][0] + i * 4096 + wave * 1024);
      }
      {  // V
        const int row  = db >> 7;
        const int colb = (db & 127) ^ ((row & 7) << 4);
        cp16(Vb + (size_t)row * S_ + kb * 64 + (colb >> 1),
             (char*)&Vld[buf][0] + i * 4096 + wave * 1024);
      }
    }
  };

  const int kswz = (q31 & 15) << 4;   // K-read swizzle (rows kt*32+q31)
  const int vswz = (q31 & 7) << 4;    // V-read swizzle (rows dj*32+q31)

  for (int half = 0; half < 2; ++half) {
    const int qt = half ? (15 - bx) : bx;   // 128-row q-tile, 0..15
    const int nkb = 2 * (qt + 1);
    const int qg = qt * 128 + wave * 32 + q31;   // this lane's q row (global)

    const unsigned short* qbase =
        Qr + ((size_t)(b * H_ + hh) * S_ + qg) * HD_;
    bf16x8 qf[8];
#pragma unroll
    for (int t = 0; t < 8; ++t) qf[t] = ld8(qbase + t * 16 + h * 8);

    f32x16 acc_o[4] = {};
    float m = -1e30f, lpart = 0.f;

    stage(0, 0);
    __syncthreads();

    for (int kb = 0; kb < nkb; ++kb) {
      const int cur = kb & 1;
      if (kb + 1 < nkb) stage(cur ^ 1, kb + 1);   // prefetch next tile FIRST

      const char* Kc = (const char*)&Kld[cur][0];
      const char* Vc = (const char*)&Vld[cur][0];

      // S^T = K Q^T (scale*log2e folded into Q upstream)
      f32x16 accs0 = {}, accs1 = {};
      __builtin_amdgcn_s_setprio(1);
#pragma unroll
      for (int t = 0; t < 8; ++t) {
        const int hd2 = t * 32 + h * 16;
        bf16x8 kf0 = ld8b(Kc, ((q31 << 8) + hd2) ^ kswz);
        bf16x8 kf1 = ld8b(Kc, (((32 + q31) << 8) + hd2) ^ kswz);
        accs0 = __builtin_amdgcn_mfma_f32_32x32x16_bf16(kf0, qf[t], accs0, 0, 0, 0);
        accs1 = __builtin_amdgcn_mfma_f32_32x32x16_bf16(kf1, qf[t], accs1, 0, 0, 0);
      }
      __builtin_amdgcn_s_setprio(0);

      // causal mask (diagonal tiles only; k index = kb*64 + kt*32 + crow)
      if (kb >= 2 * qt) {
        const int kbase = kb * 64 + 4 * h;
#pragma unroll
        for (int reg = 0; reg < 16; ++reg) {
          const int k0 = kbase + (reg & 3) + 8 * (reg >> 2);
          if (k0 > qg)      accs0[reg] = -1e30f;
          if (k0 + 32 > qg) accs1[reg] = -1e30f;
        }
      }

      // per-lane max over this lane's 32 k-values (half the row)
      float mx = -1e30f;
#pragma unroll
      for (int reg = 0; reg < 16; ++reg)
        mx = fmaxf(mx, fmaxf(accs0[reg], accs1[reg]));
      if (!__all(mx <= m + 8.f)) {   // rare: running max grew
        float mxo = __shfl_xor(mx, 32, 64);      // partner half, same q
        float mnew = fmaxf(m, fmaxf(mx, mxo));
        float corr = exp2a(m - mnew);
        m = mnew;
        lpart *= corr;
#pragma unroll
        for (int reg = 0; reg < 16; ++reg) {
          const int crow = (reg & 3) + 8 * (reg >> 2) + 4 * h;
          float cw = __shfl(corr, crow, 64);     // corr lives at lane q=crow
#pragma unroll
          for (int dj = 0; dj < 4; ++dj) acc_o[dj][reg] *= cw;
        }
      }

      // P = exp2(S - m) -> bf16 PA fragments fully in-register
      bf16x8 pa[4];
#pragma unroll
      for (int ks = 0; ks < 4; ++ks) {
        float e[8];
#pragma unroll
        for (int j = 0; j < 8; ++j) {
          float s = (ks < 2) ? accs0[8 * (ks & 1) + j] : accs1[8 * (ks & 1) + j];
          e[j] = exp2a(s - m);
          lpart += e[j];
        }
        unsigned w01 = cvtpk(e[0], e[1]);
        unsigned w23 = cvtpk(e[2], e[3]);
        unsigned w45 = cvtpk(e[4], e[5]);
        unsigned w67 = cvtpk(e[6], e[7]);
        asm volatile("v_permlane32_swap_b32 %0, %1" : "+v"(w01), "+v"(w45));
        asm volatile("v_permlane32_swap_b32 %0, %1" : "+v"(w23), "+v"(w67));
        union { unsigned u[4]; bf16x8 v; } pu;
        pu.u[0] = w01; pu.u[1] = w23; pu.u[2] = w45; pu.u[3] = w67;
        pa[ks] = pu.v;
      }

      // O += P V  (V as B-operand straight from Vld)
      __builtin_amdgcn_s_setprio(1);
#pragma unroll
      for (int dj = 0; dj < 4; ++dj) {
        const int vrow = (dj * 32 + q31) << 7;
#pragma unroll
        for (int ks = 0; ks < 4; ++ks) {
          bf16x8 vf = ld8b(Vc, (vrow + ks * 32 + h * 16) ^ vswz);
          acc_o[dj] = __builtin_amdgcn_mfma_f32_32x32x16_bf16(pa[ks], vf, acc_o[dj], 0, 0, 0);
        }
      }
      __builtin_amdgcn_s_setprio(0);

      __syncthreads();  // lands prefetch + separates buffer reuse
    }

    // finish: combine half-row sums, redistribute 1/l by output row, store
    float lsum = lpart + __shfl_xor(lpart, 32, 64);
    float linv = 1.f / lsum;
#pragma unroll
    for (int reg = 0; reg < 16; ++reg) {
      const int crow = (reg & 3) + 8 * (reg >> 2) + 4 * h;
      float lv = __shfl(linv, crow, 64);
      size_t rowoff =
          (size_t)(b * S_ + qt * 128 + wave * 32 + crow) * (H_ * HD_) + hh * HD_ + q31;
#pragma unroll
      for (int dj = 0; dj < 4; ++dj)
        O[rowoff + dj * 32] = f2bf(acc_o[dj][reg] * lv);
    }
  }
}

// Diagnostic: if ws_size is too small, fill fp32 output with sentinel 12345.
__global__ void fill_sentinel(float* __restrict__ O, int n) {
  int i = blockIdx.x * 256 + threadIdx.x;
  if (i < n) O[i] = 12345.0f;
}

// ---------------------------------------------------------------------------
extern "C" void kernel_launch(void* const* d_in, const int* in_sizes, int n_in,
                              void* d_out, int out_size, void* d_ws, size_t ws_size,
                              hipStream_t stream) {
  const float* hidden = (const float*)d_in[0]; // [B,S,D] fp32
  const float* wqkv   = (const float*)d_in[1]; // [6144,4096] fp32
  const float* wdense = (const float*)d_in[2]; // [4096,4096] fp32
  float* out = (float*)d_out;                  // [B,S,4096] fp32

  const size_t NEED = 134217728;
  if (ws_size < NEED) {
    fill_sentinel<<<dim3((out_size + 255) / 256), dim3(256), 0, stream>>>(out, out_size);
    return;
  }

  char* ws = (char*)d_ws;
  // Phase 1 layout
  unsigned short* Hb    = (unsigned short*)(ws);                 // 33,554,432 B
  unsigned short* Wqb   = (unsigned short*)(ws + 33554432);      // 50,331,648 B
  unsigned short* fused = (unsigned short*)(ws + 83886080);      // 50,331,648 B
  // Phase 2 layout (after GEMM1: Hb/Wqb dead; Wdb written AFTER GEMM1!)
  unsigned short* Qr    = (unsigned short*)(ws);                 // 33,554,432 B
  unsigned short* Kr    = (unsigned short*)(ws + 33554432);      //  8,388,608 B
  unsigned short* Vt    = (unsigned short*)(ws + 41943040);      //  8,388,608 B
  unsigned short* Wdb   = (unsigned short*)(ws + 50331648);      // 33,554,432 B
  unsigned short* attn_out = (unsigned short*)(ws + 83886080);   // 33,554,432 B (over fused)

  const int nH4 = B_ * S_ * D_ / 4;   // 4,194,304
  const int nQ4 = NE_ * D_ / 4;       // 6,291,456
  const int nD4 = D_ * D_ / 4;        // 4,194,304

  cvt2_f32_bf16<<<dim3((nH4 + nQ4 + 255) / 256), dim3(256), 0, stream>>>(
      hidden, Hb, nH4, wqkv, Wqb, nQ4);

  gemm256<unsigned short, 192><<<dim3(NE_ / 192, (B_ * S_) / 256), dim3(512), 0, stream>>>(
      Hb, Wqb, fused, B_ * S_, NE_);

  rope_scatter_cvt<<<dim3((ROPE_N + nD4 + 255) / 256), dim3(256), 0, stream>>>(
      fused, Qr, Kr, Vt, wdense, Wdb, nD4);

  attn_fwd<<<dim3(8, H_, B_), dim3(256), 0, stream>>>(Qr, Kr, Vt, attn_out);

  gemm256<float, 256><<<dim3(D_ / 256, (B_ * S_) / 256), dim3(512), 0, stream>>>(
      attn_out, Wdb, out, B_ * S_, D_);
}

// Round 17
// 473.246 us; speedup vs baseline: 1.1136x; 1.0027x over previous
//
#include <hip/hip_runtime.h>

#define B_   2
#define S_   2048
#define D_   4096
#define H_   32
#define KVH_ 8
#define HD_  128
#define NE_  6144   // (KVH*2+H)*HD

using f32x4  = __attribute__((ext_vector_type(4))) float;
using f32x16 = __attribute__((ext_vector_type(16))) float;
using bf16x8 = __attribute__((ext_vector_type(8))) __bf16;
using u16x8  = __attribute__((ext_vector_type(8))) unsigned short;

__device__ __forceinline__ unsigned short f2bf(float f) {
  union { float f; unsigned u; } v; v.f = f;
  unsigned r = v.u + 0x7FFFu + ((v.u >> 16) & 1u);
  return (unsigned short)(r >> 16);
}
__device__ __forceinline__ float bf2f(unsigned short h) {
  union { unsigned u; float f; } v; v.u = ((unsigned)h) << 16; return v.f;
}
__device__ __forceinline__ bf16x8 ld8(const unsigned short* p) {
  return *reinterpret_cast<const bf16x8*>(p);
}
__device__ __forceinline__ bf16x8 ld8b(const void* base, int byte_off) {
  return *reinterpret_cast<const bf16x8*>((const char*)base + byte_off);
}
__device__ __forceinline__ void cp16(const void* g, void* l) {
  __builtin_amdgcn_global_load_lds(
      (const __attribute__((address_space(1))) void*)g,
      (__attribute__((address_space(3))) void*)l, 16, 0, 0);
}
__device__ __forceinline__ float exp2a(float x) {   // 2^x via v_exp_f32
  float r; asm("v_exp_f32 %0, %1" : "=v"(r) : "v"(x)); return r;
}
__device__ __forceinline__ unsigned cvtpk(float lo, float hi) { // 2xf32 -> 2xbf16
  unsigned r; asm("v_cvt_pk_bf16_f32 %0, %1, %2" : "=v"(r) : "v"(lo), "v"(hi));
  return r;
}

#define SC2F 0.12751652f   // (1/sqrt(128)) * log2(e)

// ---------------------------------------------------------------------------
// Two segments in one launch (dests must be disjoint!).
// ---------------------------------------------------------------------------
__global__ __launch_bounds__(256) void cvt2_f32_bf16(
    const float* __restrict__ s0, unsigned short* __restrict__ d0, int n0,
    const float* __restrict__ s1, unsigned short* __restrict__ d1, int n1)
{
  int i = blockIdx.x * 256 + threadIdx.x;
  const float* src; unsigned short* dst;
  if (i < n0) { src = s0; dst = d0; }
  else        { i -= n0; if (i >= n1) return; src = s1; dst = d1; }
  f32x4 v = *reinterpret_cast<const f32x4*>(src + (size_t)i * 4);
  ushort4 o;
  o.x = f2bf(v[0]); o.y = f2bf(v[1]); o.z = f2bf(v[2]); o.w = f2bf(v[3]);
  *reinterpret_cast<ushort4*>(dst + (size_t)i * 4) = o;
}

// ---------------------------------------------------------------------------
// 256xNT-tile 8-phase GEMM, DEEP-PIPELINED (r17).
// Phase-major A-read order: m-frag rows = mp*32 + wr*16 (mp = p*2+j), so ALL
// waves read A-half h0 in phases 0-1 and h1 in phases 2-3 of each tile. Each
// A/B half frees one phase after its reads -> uniform 1-stage-per-phase
// rotation with 5-7 phases of flight per load (was 2-4):
//   P1:A(1,h1,t1) P2:B(0,c01,tn0) P3:A(0,h0,tn0) P4:B(0,c>=2,tn0)
//   P5:A(0,h1,tn0) P6:B(1,c01,tn1) P7:A(1,h0,tn1) P8:B(1,c>=2,tn1)
// Per-wave vmcnt proofs (invariant: iter entry = NB+4 outstanding =
// {A(0,h1,t0):2, B(1,t1):NB, A(1,h0,t1):2}):
//   steady:  P2/P6: vmcnt(NB+6); P4/P8: vmcnt(NB+4); prologue: vmcnt(NB+4)
//   last it: P2: vmcnt(NB+4); P4: vmcnt(2); P6: vmcnt(0); P8: none
// ---------------------------------------------------------------------------
template <typename OutT, int NT>
__global__ __launch_bounds__(512, 2) void gemm256(
    const unsigned short* __restrict__ A,
    const unsigned short* __restrict__ Bw,
    OutT* __restrict__ C, int M, int N)
{
  constexpr int K  = 4096;
  constexpr int NI = (K / 64) / 2;
  constexpr int NB = NT / 64;
  constexpr int NN = NT / 64;
  constexpr int WN = NT / 4;
  constexpr int BBUF = NT * 128;
  __shared__ __align__(16) char lds[65536 + 2 * BBUF];

  const int tid  = threadIdx.x;
  const int lane = tid & 63;
  const int wave = tid >> 6;
  const int wr = wave >> 2;
  const int wc = wave & 3;
  const int lr = lane & 15;
  const int lk = (lane >> 4) * 8;

  int id  = blockIdx.y * gridDim.x + blockIdx.x;
  const int nwg = gridDim.x * gridDim.y;
  if ((nwg & 7) == 0) { const int q = nwg >> 3; id = (id & 7) * q + (id >> 3); }
  const int row0 = (id / gridDim.x) * 256;
  const int col0 = (id % gridDim.x) * NT;

  int rwA[2], csA[2], dbA[2];
#pragma unroll
  for (int j = 0; j < 2; ++j) {
    dbA[j] = j * 8192 + tid * 16;
    rwA[j] = dbA[j] >> 7;
    csA[j] = ((dbA[j] & 127) ^ ((rwA[j] & 7) << 4)) >> 1;
  }
  auto stA = [&](int buf, int h, int t) {
#pragma unroll
    for (int j = 0; j < 2; ++j)
      cp16(A + (size_t)(row0 + h * 128 + rwA[j]) * K + t * 64 + csA[j],
           lds + buf * 32768 + h * 16384 + dbA[j]);
  };
  const int dbB = tid * 16;
  const int rwB = dbB >> 7;
  const int csB = ((dbB & 127) ^ ((rwB & 7) << 4)) >> 1;
  auto stB = [&](int buf, int c, int t) {
    cp16(Bw + (size_t)(col0 + c * 64 + rwB) * K + t * 64 + csB,
         lds + 65536 + buf * BBUF + c * 8192 + dbB);
  };

  const int cb0 = ((0 + lk) << 1) ^ ((lr & 7) << 4);
  const int cb1 = ((32 + lk) << 1) ^ ((lr & 7) << 4);
  const int aRowB = (wr * 16 + lr) * 128;      // phase-major row base
  const int bRowB = (wc * WN + lr) * 128;

  f32x4 acc[8][NN];
#pragma unroll
  for (int m = 0; m < 8; ++m)
#pragma unroll
    for (int n = 0; n < NN; ++n) acc[m][n] = (f32x4){0.f, 0.f, 0.f, 0.f};
  bf16x8 bfr[NN][2];

#define FENCE asm volatile("" ::: "memory")
#define VMC(nn) asm volatile("s_waitcnt vmcnt(" #nn ")" ::: "memory")

#define PHASE(p, buf, STAGE, WAIT)                                             \
  {                                                                            \
    if ((p) == 0) {                                                            \
      _Pragma("unroll")                                                        \
      for (int n = 0; n < NN; ++n) {                                           \
        bfr[n][0] = ld8b(lds, 65536 + (buf) * BBUF + bRowB + n * 2048 + cb0);  \
        bfr[n][1] = ld8b(lds, 65536 + (buf) * BBUF + bRowB + n * 2048 + cb1);  \
      }                                                                        \
    }                                                                          \
    bf16x8 a00 = ld8b(lds, (buf) * 32768 + (p) * 8192 + aRowB + cb0);          \
    bf16x8 a01 = ld8b(lds, (buf) * 32768 + (p) * 8192 + aRowB + cb1);          \
    bf16x8 a10 = ld8b(lds, (buf) * 32768 + (p) * 8192 + 4096 + aRowB + cb0);   \
    bf16x8 a11 = ld8b(lds, (buf) * 32768 + (p) * 8192 + 4096 + aRowB + cb1);   \
    STAGE;                                                                     \
    FENCE;                                                                     \
    __builtin_amdgcn_s_barrier();                                              \
    __builtin_amdgcn_s_setprio(1);                                             \
    _Pragma("unroll")                                                          \
    for (int n = 0; n < NN; ++n) {                                             \
      acc[(p)*2+0][n] = __builtin_amdgcn_mfma_f32_16x16x32_bf16(a00, bfr[n][0], acc[(p)*2+0][n], 0, 0, 0); \
      acc[(p)*2+0][n] = __builtin_amdgcn_mfma_f32_16x16x32_bf16(a01, bfr[n][1], acc[(p)*2+0][n], 0, 0, 0); \
      acc[(p)*2+1][n] = __builtin_amdgcn_mfma_f32_16x16x32_bf16(a10, bfr[n][0], acc[(p)*2+1][n], 0, 0, 0); \
      acc[(p)*2+1][n] = __builtin_amdgcn_mfma_f32_16x16x32_bf16(a11, bfr[n][1], acc[(p)*2+1][n], 0, 0, 0); \
    }                                                                          \
    __builtin_amdgcn_s_setprio(0);                                             \
    WAIT;                                                                      \
    FENCE;                                                                     \
    __builtin_amdgcn_s_barrier();                                              \
  }

  // Prologue: B(0,t0), A(0,t0,h0+h1), B(1,t1), A(1,h0,t1). A(1,h1,t1) comes
  // at iter0-P1. Wait vmcnt(NB+4) proves B(0,t0)+A(0,h0,t0) before P1.
#pragma unroll
  for (int c = 0; c < NB; ++c) stB(0, c, 0);
  stA(0, 0, 0); stA(0, 1, 0);
#pragma unroll
  for (int c = 0; c < NB; ++c) stB(1, c, 1);
  stA(1, 0, 1);
  if constexpr (NB == 4) { VMC(8); } else { VMC(7); }   // NB+4
  FENCE;
  __builtin_amdgcn_s_barrier();

  for (int i = 0; i < NI; ++i) {
    const int t1  = 2 * i + 1;
    const int tn0 = 2 * i + 2;
    const int tn1 = 2 * i + 3;
    const bool pre = (i + 1 < NI);
    // K-tile 2i in buf0
    PHASE(0, 0, { stA(1, 1, t1); }, {});
    PHASE(1, 0, { if (pre) { stB(0, 0, tn0); stB(0, 1, tn0); } },
          { if (pre) { if constexpr (NB == 4) VMC(10); else VMC(9); }      // NB+6
            else     { if constexpr (NB == 4) VMC(8);  else VMC(7); } });  // NB+4
    PHASE(2, 0, { if (pre) stA(0, 0, tn0); }, {});
    PHASE(3, 0, { if (pre) { _Pragma("unroll") for (int c = 2; c < NB; ++c) stB(0, c, tn0); } },
          { if (pre) { if constexpr (NB == 4) VMC(8); else VMC(7); }       // NB+4
            else     { VMC(2); } });
    // K-tile 2i+1 in buf1
    PHASE(0, 1, { if (pre) stA(0, 1, tn0); }, {});
    PHASE(1, 1, { if (pre) { stB(1, 0, tn1); stB(1, 1, tn1); } },
          { if (pre) { if constexpr (NB == 4) VMC(10); else VMC(9); }      // NB+6
            else     { VMC(0); } });
    PHASE(2, 1, { if (pre) stA(1, 0, tn1); }, {});
    PHASE(3, 1, { if (pre) { _Pragma("unroll") for (int c = 2; c < NB; ++c) stB(1, c, tn1); } },
          { if (pre) { if constexpr (NB == 4) VMC(8); else VMC(7); } });   // NB+4
  }
#undef PHASE
#undef FENCE
#undef VMC

  // C-write under phase-major frag map: row = m*32 + wr*16 + orow + r
  const int orow = (lane >> 4) * 4;
#pragma unroll
  for (int m = 0; m < 8; ++m) {
    const int gr0 = row0 + m * 32 + wr * 16 + orow;
#pragma unroll
    for (int n = 0; n < NN; ++n) {
      const int gc = col0 + wc * WN + n * 16 + lr;
#pragma unroll
      for (int r = 0; r < 4; ++r) {
        float val = acc[m][n][r];
        if constexpr (sizeof(OutT) == 2)
          C[(size_t)(gr0 + r) * N + gc] = f2bf(val);
        else
          C[(size_t)(gr0 + r) * N + gc] = val;
      }
    }
  }
}

// ---------------------------------------------------------------------------
// Fused rope_scatter + wdense cvt (frozen).
// ---------------------------------------------------------------------------
#define ROPE_N (B_ * S_ * 48 * 8)
__global__ __launch_bounds__(256) void rope_scatter_cvt(
    const unsigned short* __restrict__ fused,
    unsigned short* __restrict__ Qr,
    unsigned short* __restrict__ Kr,
    unsigned short* __restrict__ Vt,
    const float* __restrict__ wdense,
    unsigned short* __restrict__ Wdb,
    int nD4)
{
  int idx = blockIdx.x * 256 + threadIdx.x;
  if (idx >= ROPE_N) {
    int i = idx - ROPE_N;
    if (i >= nD4) return;
    f32x4 v = *reinterpret_cast<const f32x4*>(wdense + (size_t)i * 4);
    ushort4 o;
    o.x = f2bf(v[0]); o.y = f2bf(v[1]); o.z = f2bf(v[2]); o.w = f2bf(v[3]);
    *reinterpret_cast<ushort4*>(Wdb + (size_t)i * 4) = o;
    return;
  }
  int dg = idx & 7;
  int t = idx >> 3;
  int e = t % 48;
  int bs = t / 48;
  int s = bs % S_;
  int b = bs / S_;
  int kvh = e / 6, j = e % 6;
  const unsigned short* src = fused + (size_t)bs * NE_ + e * 128 + dg * 8;
  u16x8 lo = *reinterpret_cast<const u16x8*>(src);
  u16x8 hi = *reinterpret_cast<const u16x8*>(src + 64);
  if (j == 5) {
    size_t base = (size_t)(b * KVH_ + kvh) * HD_ * S_ + s;
#pragma unroll
    for (int jj = 0; jj < 8; ++jj) {
      Vt[base + (size_t)(dg * 8 + jj) * S_]      = lo[jj];
      Vt[base + (size_t)(dg * 8 + jj + 64) * S_] = hi[jj];
    }
  } else {
    const float sc = (j == 4) ? 1.0f : SC2F;
    u16x8 olo, ohi;
#pragma unroll
    for (int jj = 0; jj < 8; ++jj) {
      int d = dg * 8 + jj;
      float x1 = bf2f(lo[jj]), x2 = bf2f(hi[jj]);
      float inv = __expf(-(float)d * (9.2103403719761836f / 64.0f));
      float ang = (float)s * inv;
      float sn, c;
      sincosf(ang, &sn, &c);
      olo[jj] = f2bf((x1 * c - x2 * sn) * sc);
      ohi[jj] = f2bf((x2 * c + x1 * sn) * sc);
    }
    unsigned short* dst;
    if (j == 4) dst = Kr + ((size_t)(b * KVH_ + kvh) * S_ + s) * HD_;
    else        dst = Qr + ((size_t)(b * H_ + kvh * 4 + j) * S_ + s) * HD_;
    *reinterpret_cast<u16x8*>(dst + dg * 8)      = olo;
    *reinterpret_cast<u16x8*>(dst + dg * 8 + 64) = ohi;
  }
}

// ---------------------------------------------------------------------------
// Causal GQA flash attention — 32x32 swapped-QK^T, in-register softmax (T12).
// (r16 — frozen; 474.5 µs total, attn ~84 µs.)
// ---------------------------------------------------------------------------
__global__ __launch_bounds__(256, 2) void attn_fwd(
    const unsigned short* __restrict__ Qr,
    const unsigned short* __restrict__ Kr,
    const unsigned short* __restrict__ Vt,
    unsigned short* __restrict__ O)
{
  __shared__ __align__(16) unsigned short Kld[2][64 * 128];
  __shared__ __align__(16) unsigned short Vld[2][128 * 64];

  const int tid  = threadIdx.x;
  const int lane = tid & 63;
  const int wave = tid >> 6;
  const int bx = blockIdx.x;
  const int hh = blockIdx.y;
  const int b  = blockIdx.z;
  const int kvh = hh >> 2;
  const int q31 = lane & 31;
  const int h   = lane >> 5;

  const unsigned short* Kb = Kr + (size_t)(b * KVH_ + kvh) * S_ * HD_;
  const unsigned short* Vb = Vt + (size_t)(b * KVH_ + kvh) * HD_ * S_;

  auto stage = [&](int buf, int kb) {
#pragma unroll
    for (int i = 0; i < 4; ++i) {
      const int db = i * 4096 + tid * 16;
      {  // K
        const int row  = db >> 8;
        const int colb = (db & 255) ^ ((row & 15) << 4);
        cp16(Kb + (size_t)(kb * 64 + row) * HD_ + (colb >> 1),
             (char*)&Kld[buf][0] + i * 4096 + wave * 1024);
      }
      {  // V
        const int row  = db >> 7;
        const int colb = (db & 127) ^ ((row & 7) << 4);
        cp16(Vb + (size_t)row * S_ + kb * 64 + (colb >> 1),
             (char*)&Vld[buf][0] + i * 4096 + wave * 1024);
      }
    }
  };

  const int kswz = (q31 & 15) << 4;
  const int vswz = (q31 & 7) << 4;

  for (int half = 0; half < 2; ++half) {
    const int qt = half ? (15 - bx) : bx;
    const int nkb = 2 * (qt + 1);
    const int qg = qt * 128 + wave * 32 + q31;

    const unsigned short* qbase =
        Qr + ((size_t)(b * H_ + hh) * S_ + qg) * HD_;
    bf16x8 qf[8];
#pragma unroll
    for (int t = 0; t < 8; ++t) qf[t] = ld8(qbase + t * 16 + h * 8);

    f32x16 acc_o[4] = {};
    float m = -1e30f, lpart = 0.f;

    stage(0, 0);
    __syncthreads();

    for (int kb = 0; kb < nkb; ++kb) {
      const int cur = kb & 1;
      if (kb + 1 < nkb) stage(cur ^ 1, kb + 1);

      const char* Kc = (const char*)&Kld[cur][0];
      const char* Vc = (const char*)&Vld[cur][0];

      f32x16 accs0 = {}, accs1 = {};
      __builtin_amdgcn_s_setprio(1);
#pragma unroll
      for (int t = 0; t < 8; ++t) {
        const int hd2 = t * 32 + h * 16;
        bf16x8 kf0 = ld8b(Kc, ((q31 << 8) + hd2) ^ kswz);
        bf16x8 kf1 = ld8b(Kc, (((32 + q31) << 8) + hd2) ^ kswz);
        accs0 = __builtin_amdgcn_mfma_f32_32x32x16_bf16(kf0, qf[t], accs0, 0, 0, 0);
        accs1 = __builtin_amdgcn_mfma_f32_32x32x16_bf16(kf1, qf[t], accs1, 0, 0, 0);
      }
      __builtin_amdgcn_s_setprio(0);

      if (kb >= 2 * qt) {
        const int kbase = kb * 64 + 4 * h;
#pragma unroll
        for (int reg = 0; reg < 16; ++reg) {
          const int k0 = kbase + (reg & 3) + 8 * (reg >> 2);
          if (k0 > qg)      accs0[reg] = -1e30f;
          if (k0 + 32 > qg) accs1[reg] = -1e30f;
        }
      }

      float mx = -1e30f;
#pragma unroll
      for (int reg = 0; reg < 16; ++reg)
        mx = fmaxf(mx, fmaxf(accs0[reg], accs1[reg]));
      if (!__all(mx <= m + 8.f)) {
        float mxo = __shfl_xor(mx, 32, 64);
        float mnew = fmaxf(m, fmaxf(mx, mxo));
        float corr = exp2a(m - mnew);
        m = mnew;
        lpart *= corr;
#pragma unroll
        for (int reg = 0; reg < 16; ++reg) {
          const int crow = (reg & 3) + 8 * (reg >> 2) + 4 * h;
          float cw = __shfl(corr, crow, 64);
#pragma unroll
          for (int dj = 0; dj < 4; ++dj) acc_o[dj][reg] *= cw;
        }
      }

      bf16x8 pa[4];
#pragma unroll
      for (int ks = 0; ks < 4; ++ks) {
        float e[8];
#pragma unroll
        for (int j = 0; j < 8; ++j) {
          float s = (ks < 2) ? accs0[8 * (ks & 1) + j] : accs1[8 * (ks & 1) + j];
          e[j] = exp2a(s - m);
          lpart += e[j];
        }
        unsigned w01 = cvtpk(e[0], e[1]);
        unsigned w23 = cvtpk(e[2], e[3]);
        unsigned w45 = cvtpk(e[4], e[5]);
        unsigned w67 = cvtpk(e[6], e[7]);
        asm volatile("v_permlane32_swap_b32 %0, %1" : "+v"(w01), "+v"(w45));
        asm volatile("v_permlane32_swap_b32 %0, %1" : "+v"(w23), "+v"(w67));
        union { unsigned u[4]; bf16x8 v; } pu;
        pu.u[0] = w01; pu.u[1] = w23; pu.u[2] = w45; pu.u[3] = w67;
        pa[ks] = pu.v;
      }

      __builtin_amdgcn_s_setprio(1);
#pragma unroll
      for (int dj = 0; dj < 4; ++dj) {
        const int vrow = (dj * 32 + q31) << 7;
#pragma unroll
        for (int ks = 0; ks < 4; ++ks) {
          bf16x8 vf = ld8b(Vc, (vrow + ks * 32 + h * 16) ^ vswz);
          acc_o[dj] = __builtin_amdgcn_mfma_f32_32x32x16_bf16(pa[ks], vf, acc_o[dj], 0, 0, 0);
        }
      }
      __builtin_amdgcn_s_setprio(0);

      __syncthreads();
    }

    float lsum = lpart + __shfl_xor(lpart, 32, 64);
    float linv = 1.f / lsum;
#pragma unroll
    for (int reg = 0; reg < 16; ++reg) {
      const int crow = (reg & 3) + 8 * (reg >> 2) + 4 * h;
      float lv = __shfl(linv, crow, 64);
      size_t rowoff =
          (size_t)(b * S_ + qt * 128 + wave * 32 + crow) * (H_ * HD_) + hh * HD_ + q31;
#pragma unroll
      for (int dj = 0; dj < 4; ++dj)
        O[rowoff + dj * 32] = f2bf(acc_o[dj][reg] * lv);
    }
  }
}

// Diagnostic: if ws_size is too small, fill fp32 output with sentinel 12345.
__global__ void fill_sentinel(float* __restrict__ O, int n) {
  int i = blockIdx.x * 256 + threadIdx.x;
  if (i < n) O[i] = 12345.0f;
}

// ---------------------------------------------------------------------------
extern "C" void kernel_launch(void* const* d_in, const int* in_sizes, int n_in,
                              void* d_out, int out_size, void* d_ws, size_t ws_size,
                              hipStream_t stream) {
  const float* hidden = (const float*)d_in[0]; // [B,S,D] fp32
  const float* wqkv   = (const float*)d_in[1]; // [6144,4096] fp32
  const float* wdense = (const float*)d_in[2]; // [4096,4096] fp32
  float* out = (float*)d_out;                  // [B,S,4096] fp32

  const size_t NEED = 134217728;
  if (ws_size < NEED) {
    fill_sentinel<<<dim3((out_size + 255) / 256), dim3(256), 0, stream>>>(out, out_size);
    return;
  }

  char* ws = (char*)d_ws;
  // Phase 1 layout
  unsigned short* Hb    = (unsigned short*)(ws);                 // 33,554,432 B
  unsigned short* Wqb   = (unsigned short*)(ws + 33554432);      // 50,331,648 B
  unsigned short* fused = (unsigned short*)(ws + 83886080);      // 50,331,648 B
  // Phase 2 layout (after GEMM1: Hb/Wqb dead; Wdb written AFTER GEMM1!)
  unsigned short* Qr    = (unsigned short*)(ws);                 // 33,554,432 B
  unsigned short* Kr    = (unsigned short*)(ws + 33554432);      //  8,388,608 B
  unsigned short* Vt    = (unsigned short*)(ws + 41943040);      //  8,388,608 B
  unsigned short* Wdb   = (unsigned short*)(ws + 50331648);      // 33,554,432 B
  unsigned short* attn_out = (unsigned short*)(ws + 83886080);   // 33,554,432 B (over fused)

  const int nH4 = B_ * S_ * D_ / 4;   // 4,194,304
  const int nQ4 = NE_ * D_ / 4;       // 6,291,456
  const int nD4 = D_ * D_ / 4;        // 4,194,304

  cvt2_f32_bf16<<<dim3((nH4 + nQ4 + 255) / 256), dim3(256), 0, stream>>>(
      hidden, Hb, nH4, wqkv, Wqb, nQ4);

  gemm256<unsigned short, 192><<<dim3(NE_ / 192, (B_ * S_) / 256), dim3(512), 0, stream>>>(
      Hb, Wqb, fused, B_ * S_, NE_);

  rope_scatter_cvt<<<dim3((ROPE_N + nD4 + 255) / 256), dim3(256), 0, stream>>>(
      fused, Qr, Kr, Vt, wdense, Wdb, nD4);

  attn_fwd<<<dim3(8, H_, B_), dim3(256), 0, stream>>>(Qr, Kr, Vt, attn_out);

  gemm256<float, 256><<<dim3(D_ / 256, (B_ * S_) / 256), dim3(512), 0, stream>>>(
      attn_out, Wdb, out, B_ * S_, D_);
}

// Round 18
// 468.952 us; speedup vs baseline: 1.1238x; 1.0092x over previous
//
#include <hip/hip_runtime.h>

#define B_   2
#define S_   2048
#define D_   4096
#define H_   32
#define KVH_ 8
#define HD_  128
#define NE_  6144   // (KVH*2+H)*HD

using f32x4  = __attribute__((ext_vector_type(4))) float;
using f32x16 = __attribute__((ext_vector_type(16))) float;
using bf16x8 = __attribute__((ext_vector_type(8))) __bf16;
using u16x8  = __attribute__((ext_vector_type(8))) unsigned short;

__device__ __forceinline__ unsigned short f2bf(float f) {
  union { float f; unsigned u; } v; v.f = f;
  unsigned r = v.u + 0x7FFFu + ((v.u >> 16) & 1u);
  return (unsigned short)(r >> 16);
}
__device__ __forceinline__ float bf2f(unsigned short h) {
  union { unsigned u; float f; } v; v.u = ((unsigned)h) << 16; return v.f;
}
__device__ __forceinline__ bf16x8 ld8(const unsigned short* p) {
  return *reinterpret_cast<const bf16x8*>(p);
}
__device__ __forceinline__ bf16x8 ld8b(const void* base, int byte_off) {
  return *reinterpret_cast<const bf16x8*>((const char*)base + byte_off);
}
__device__ __forceinline__ void cp16(const void* g, void* l) {
  __builtin_amdgcn_global_load_lds(
      (const __attribute__((address_space(1))) void*)g,
      (__attribute__((address_space(3))) void*)l, 16, 0, 0);
}
__device__ __forceinline__ float exp2a(float x) {   // 2^x via v_exp_f32
  float r; asm("v_exp_f32 %0, %1" : "=v"(r) : "v"(x)); return r;
}
__device__ __forceinline__ unsigned cvtpk(float lo, float hi) { // 2xf32 -> 2xbf16
  unsigned r; asm("v_cvt_pk_bf16_f32 %0, %1, %2" : "=v"(r) : "v"(lo), "v"(hi));
  return r;
}

#define SC2F 0.12751652f   // (1/sqrt(128)) * log2(e)

// ---------------------------------------------------------------------------
// Two segments in one launch (dests must be disjoint!).
// ---------------------------------------------------------------------------
__global__ __launch_bounds__(256) void cvt2_f32_bf16(
    const float* __restrict__ s0, unsigned short* __restrict__ d0, int n0,
    const float* __restrict__ s1, unsigned short* __restrict__ d1, int n1)
{
  int i = blockIdx.x * 256 + threadIdx.x;
  const float* src; unsigned short* dst;
  if (i < n0) { src = s0; dst = d0; }
  else        { i -= n0; if (i >= n1) return; src = s1; dst = d1; }
  f32x4 v = *reinterpret_cast<const f32x4*>(src + (size_t)i * 4);
  ushort4 o;
  o.x = f2bf(v[0]); o.y = f2bf(v[1]); o.z = f2bf(v[2]); o.w = f2bf(v[3]);
  *reinterpret_cast<ushort4*>(dst + (size_t)i * 4) = o;
}

// ---------------------------------------------------------------------------
// 256xNT-tile 8-phase GEMM, SINGLE-BARRIER phases (r18).
// r17's deep-pipeline rotation kept; the mid-phase barrier is DELETED:
// MFMA operands are the wave's OWN ds_reads (lgkmcnt covers them), and all
// cross-wave write->read hazards are proven by counted-vmcnt + the phase-END
// barrier. Region audit (single-barrier skew = all waves inside the same
// phase body): A stages always target the non-read buffer; B stages land >=1
// full phase body + barrier after that region's last read issue (>> LDS read
// latency). 8 barriers/iter (was 16).
// Rotation: P1:A(1,h1,t1) P2:B(0,c01,tn0) P3:A(0,h0,tn0) P4:B(0,c>=2,tn0)
//           P5:A(0,h1,tn0) P6:B(1,c01,tn1) P7:A(1,h0,tn1) P8:B(1,c>=2,tn1)
// Waits: P2/P6 vmcnt(NB+6); P4/P8 vmcnt(NB+4); last iter P2 NB+4, P4 2,
// P6 0, P8 none. Prologue vmcnt(NB+4).
// ---------------------------------------------------------------------------
template <typename OutT, int NT>
__global__ __launch_bounds__(512, 2) void gemm256(
    const unsigned short* __restrict__ A,
    const unsigned short* __restrict__ Bw,
    OutT* __restrict__ C, int M, int N)
{
  constexpr int K  = 4096;
  constexpr int NI = (K / 64) / 2;
  constexpr int NB = NT / 64;
  constexpr int NN = NT / 64;
  constexpr int WN = NT / 4;
  constexpr int BBUF = NT * 128;
  __shared__ __align__(16) char lds[65536 + 2 * BBUF];

  const int tid  = threadIdx.x;
  const int lane = tid & 63;
  const int wave = tid >> 6;
  const int wr = wave >> 2;
  const int wc = wave & 3;
  const int lr = lane & 15;
  const int lk = (lane >> 4) * 8;

  int id  = blockIdx.y * gridDim.x + blockIdx.x;
  const int nwg = gridDim.x * gridDim.y;
  if ((nwg & 7) == 0) { const int q = nwg >> 3; id = (id & 7) * q + (id >> 3); }
  const int row0 = (id / gridDim.x) * 256;
  const int col0 = (id % gridDim.x) * NT;

  int rwA[2], csA[2], dbA[2];
#pragma unroll
  for (int j = 0; j < 2; ++j) {
    dbA[j] = j * 8192 + tid * 16;
    rwA[j] = dbA[j] >> 7;
    csA[j] = ((dbA[j] & 127) ^ ((rwA[j] & 7) << 4)) >> 1;
  }
  auto stA = [&](int buf, int h, int t) {
#pragma unroll
    for (int j = 0; j < 2; ++j)
      cp16(A + (size_t)(row0 + h * 128 + rwA[j]) * K + t * 64 + csA[j],
           lds + buf * 32768 + h * 16384 + dbA[j]);
  };
  const int dbB = tid * 16;
  const int rwB = dbB >> 7;
  const int csB = ((dbB & 127) ^ ((rwB & 7) << 4)) >> 1;
  auto stB = [&](int buf, int c, int t) {
    cp16(Bw + (size_t)(col0 + c * 64 + rwB) * K + t * 64 + csB,
         lds + 65536 + buf * BBUF + c * 8192 + dbB);
  };

  const int cb0 = ((0 + lk) << 1) ^ ((lr & 7) << 4);
  const int cb1 = ((32 + lk) << 1) ^ ((lr & 7) << 4);
  const int aRowB = (wr * 16 + lr) * 128;      // phase-major row base
  const int bRowB = (wc * WN + lr) * 128;

  f32x4 acc[8][NN];
#pragma unroll
  for (int m = 0; m < 8; ++m)
#pragma unroll
    for (int n = 0; n < NN; ++n) acc[m][n] = (f32x4){0.f, 0.f, 0.f, 0.f};
  bf16x8 bfr[NN][2];

#define FENCE asm volatile("" ::: "memory")
#define VMC(nn) asm volatile("s_waitcnt vmcnt(" #nn ")" ::: "memory")

#define PHASE(p, buf, STAGE, WAIT)                                             \
  {                                                                            \
    if ((p) == 0) {                                                            \
      _Pragma("unroll")                                                        \
      for (int n = 0; n < NN; ++n) {                                           \
        bfr[n][0] = ld8b(lds, 65536 + (buf) * BBUF + bRowB + n * 2048 + cb0);  \
        bfr[n][1] = ld8b(lds, 65536 + (buf) * BBUF + bRowB + n * 2048 + cb1);  \
      }                                                                        \
    }                                                                          \
    bf16x8 a00 = ld8b(lds, (buf) * 32768 + (p) * 8192 + aRowB + cb0);          \
    bf16x8 a01 = ld8b(lds, (buf) * 32768 + (p) * 8192 + aRowB + cb1);          \
    bf16x8 a10 = ld8b(lds, (buf) * 32768 + (p) * 8192 + 4096 + aRowB + cb0);   \
    bf16x8 a11 = ld8b(lds, (buf) * 32768 + (p) * 8192 + 4096 + aRowB + cb1);   \
    STAGE;                                                                     \
    __builtin_amdgcn_s_setprio(1);                                             \
    _Pragma("unroll")                                                          \
    for (int n = 0; n < NN; ++n) {                                             \
      acc[(p)*2+0][n] = __builtin_amdgcn_mfma_f32_16x16x32_bf16(a00, bfr[n][0], acc[(p)*2+0][n], 0, 0, 0); \
      acc[(p)*2+0][n] = __builtin_amdgcn_mfma_f32_16x16x32_bf16(a01, bfr[n][1], acc[(p)*2+0][n], 0, 0, 0); \
      acc[(p)*2+1][n] = __builtin_amdgcn_mfma_f32_16x16x32_bf16(a10, bfr[n][0], acc[(p)*2+1][n], 0, 0, 0); \
      acc[(p)*2+1][n] = __builtin_amdgcn_mfma_f32_16x16x32_bf16(a11, bfr[n][1], acc[(p)*2+1][n], 0, 0, 0); \
    }                                                                          \
    __builtin_amdgcn_s_setprio(0);                                             \
    WAIT;                                                                      \
    FENCE;                                                                     \
    __builtin_amdgcn_s_barrier();                                              \
  }

  // Prologue: B(0,t0), A(0,t0,h0+h1), B(1,t1), A(1,h0,t1).
#pragma unroll
  for (int c = 0; c < NB; ++c) stB(0, c, 0);
  stA(0, 0, 0); stA(0, 1, 0);
#pragma unroll
  for (int c = 0; c < NB; ++c) stB(1, c, 1);
  stA(1, 0, 1);
  if constexpr (NB == 4) { VMC(8); } else { VMC(7); }   // NB+4
  FENCE;
  __builtin_amdgcn_s_barrier();

  for (int i = 0; i < NI; ++i) {
    const int t1  = 2 * i + 1;
    const int tn0 = 2 * i + 2;
    const int tn1 = 2 * i + 3;
    const bool pre = (i + 1 < NI);
    // K-tile 2i in buf0
    PHASE(0, 0, { stA(1, 1, t1); }, {});
    PHASE(1, 0, { if (pre) { stB(0, 0, tn0); stB(0, 1, tn0); } },
          { if (pre) { if constexpr (NB == 4) VMC(10); else VMC(9); }      // NB+6
            else     { if constexpr (NB == 4) VMC(8);  else VMC(7); } });  // NB+4
    PHASE(2, 0, { if (pre) stA(0, 0, tn0); }, {});
    PHASE(3, 0, { if (pre) { _Pragma("unroll") for (int c = 2; c < NB; ++c) stB(0, c, tn0); } },
          { if (pre) { if constexpr (NB == 4) VMC(8); else VMC(7); }       // NB+4
            else     { VMC(2); } });
    // K-tile 2i+1 in buf1
    PHASE(0, 1, { if (pre) stA(0, 1, tn0); }, {});
    PHASE(1, 1, { if (pre) { stB(1, 0, tn1); stB(1, 1, tn1); } },
          { if (pre) { if constexpr (NB == 4) VMC(10); else VMC(9); }      // NB+6
            else     { VMC(0); } });
    PHASE(2, 1, { if (pre) stA(1, 0, tn1); }, {});
    PHASE(3, 1, { if (pre) { _Pragma("unroll") for (int c = 2; c < NB; ++c) stB(1, c, tn1); } },
          { if (pre) { if constexpr (NB == 4) VMC(8); else VMC(7); } });   // NB+4
  }
#undef PHASE
#undef FENCE
#undef VMC

  // C-write under phase-major frag map: row = m*32 + wr*16 + orow + r
  const int orow = (lane >> 4) * 4;
#pragma unroll
  for (int m = 0; m < 8; ++m) {
    const int gr0 = row0 + m * 32 + wr * 16 + orow;
#pragma unroll
    for (int n = 0; n < NN; ++n) {
      const int gc = col0 + wc * WN + n * 16 + lr;
#pragma unroll
      for (int r = 0; r < 4; ++r) {
        float val = acc[m][n][r];
        if constexpr (sizeof(OutT) == 2)
          C[(size_t)(gr0 + r) * N + gc] = f2bf(val);
        else
          C[(size_t)(gr0 + r) * N + gc] = val;
      }
    }
  }
}

// ---------------------------------------------------------------------------
// Fused rope_scatter + wdense cvt (frozen).
// ---------------------------------------------------------------------------
#define ROPE_N (B_ * S_ * 48 * 8)
__global__ __launch_bounds__(256) void rope_scatter_cvt(
    const unsigned short* __restrict__ fused,
    unsigned short* __restrict__ Qr,
    unsigned short* __restrict__ Kr,
    unsigned short* __restrict__ Vt,
    const float* __restrict__ wdense,
    unsigned short* __restrict__ Wdb,
    int nD4)
{
  int idx = blockIdx.x * 256 + threadIdx.x;
  if (idx >= ROPE_N) {
    int i = idx - ROPE_N;
    if (i >= nD4) return;
    f32x4 v = *reinterpret_cast<const f32x4*>(wdense + (size_t)i * 4);
    ushort4 o;
    o.x = f2bf(v[0]); o.y = f2bf(v[1]); o.z = f2bf(v[2]); o.w = f2bf(v[3]);
    *reinterpret_cast<ushort4*>(Wdb + (size_t)i * 4) = o;
    return;
  }
  int dg = idx & 7;
  int t = idx >> 3;
  int e = t % 48;
  int bs = t / 48;
  int s = bs % S_;
  int b = bs / S_;
  int kvh = e / 6, j = e % 6;
  const unsigned short* src = fused + (size_t)bs * NE_ + e * 128 + dg * 8;
  u16x8 lo = *reinterpret_cast<const u16x8*>(src);
  u16x8 hi = *reinterpret_cast<const u16x8*>(src + 64);
  if (j == 5) {
    size_t base = (size_t)(b * KVH_ + kvh) * HD_ * S_ + s;
#pragma unroll
    for (int jj = 0; jj < 8; ++jj) {
      Vt[base + (size_t)(dg * 8 + jj) * S_]      = lo[jj];
      Vt[base + (size_t)(dg * 8 + jj + 64) * S_] = hi[jj];
    }
  } else {
    const float sc = (j == 4) ? 1.0f : SC2F;
    u16x8 olo, ohi;
#pragma unroll
    for (int jj = 0; jj < 8; ++jj) {
      int d = dg * 8 + jj;
      float x1 = bf2f(lo[jj]), x2 = bf2f(hi[jj]);
      float inv = __expf(-(float)d * (9.2103403719761836f / 64.0f));
      float ang = (float)s * inv;
      float sn, c;
      sincosf(ang, &sn, &c);
      olo[jj] = f2bf((x1 * c - x2 * sn) * sc);
      ohi[jj] = f2bf((x2 * c + x1 * sn) * sc);
    }
    unsigned short* dst;
    if (j == 4) dst = Kr + ((size_t)(b * KVH_ + kvh) * S_ + s) * HD_;
    else        dst = Qr + ((size_t)(b * H_ + kvh * 4 + j) * S_ + s) * HD_;
    *reinterpret_cast<u16x8*>(dst + dg * 8)      = olo;
    *reinterpret_cast<u16x8*>(dst + dg * 8 + 64) = ohi;
  }
}

// ---------------------------------------------------------------------------
// Causal GQA flash attention — 32x32 swapped-QK^T, in-register softmax (T12).
// (r16 — frozen; attn ~84 µs.)
// ---------------------------------------------------------------------------
__global__ __launch_bounds__(256, 2) void attn_fwd(
    const unsigned short* __restrict__ Qr,
    const unsigned short* __restrict__ Kr,
    const unsigned short* __restrict__ Vt,
    unsigned short* __restrict__ O)
{
  __shared__ __align__(16) unsigned short Kld[2][64 * 128];
  __shared__ __align__(16) unsigned short Vld[2][128 * 64];

  const int tid  = threadIdx.x;
  const int lane = tid & 63;
  const int wave = tid >> 6;
  const int bx = blockIdx.x;
  const int hh = blockIdx.y;
  const int b  = blockIdx.z;
  const int kvh = hh >> 2;
  const int q31 = lane & 31;
  const int h   = lane >> 5;

  const unsigned short* Kb = Kr + (size_t)(b * KVH_ + kvh) * S_ * HD_;
  const unsigned short* Vb = Vt + (size_t)(b * KVH_ + kvh) * HD_ * S_;

  auto stage = [&](int buf, int kb) {
#pragma unroll
    for (int i = 0; i < 4; ++i) {
      const int db = i * 4096 + tid * 16;
      {  // K
        const int row  = db >> 8;
        const int colb = (db & 255) ^ ((row & 15) << 4);
        cp16(Kb + (size_t)(kb * 64 + row) * HD_ + (colb >> 1),
             (char*)&Kld[buf][0] + i * 4096 + wave * 1024);
      }
      {  // V
        const int row  = db >> 7;
        const int colb = (db & 127) ^ ((row & 7) << 4);
        cp16(Vb + (size_t)row * S_ + kb * 64 + (colb >> 1),
             (char*)&Vld[buf][0] + i * 4096 + wave * 1024);
      }
    }
  };

  const int kswz = (q31 & 15) << 4;
  const int vswz = (q31 & 7) << 4;

  for (int half = 0; half < 2; ++half) {
    const int qt = half ? (15 - bx) : bx;
    const int nkb = 2 * (qt + 1);
    const int qg = qt * 128 + wave * 32 + q31;

    const unsigned short* qbase =
        Qr + ((size_t)(b * H_ + hh) * S_ + qg) * HD_;
    bf16x8 qf[8];
#pragma unroll
    for (int t = 0; t < 8; ++t) qf[t] = ld8(qbase + t * 16 + h * 8);

    f32x16 acc_o[4] = {};
    float m = -1e30f, lpart = 0.f;

    stage(0, 0);
    __syncthreads();

    for (int kb = 0; kb < nkb; ++kb) {
      const int cur = kb & 1;
      if (kb + 1 < nkb) stage(cur ^ 1, kb + 1);

      const char* Kc = (const char*)&Kld[cur][0];
      const char* Vc = (const char*)&Vld[cur][0];

      f32x16 accs0 = {}, accs1 = {};
      __builtin_amdgcn_s_setprio(1);
#pragma unroll
      for (int t = 0; t < 8; ++t) {
        const int hd2 = t * 32 + h * 16;
        bf16x8 kf0 = ld8b(Kc, ((q31 << 8) + hd2) ^ kswz);
        bf16x8 kf1 = ld8b(Kc, (((32 + q31) << 8) + hd2) ^ kswz);
        accs0 = __builtin_amdgcn_mfma_f32_32x32x16_bf16(kf0, qf[t], accs0, 0, 0, 0);
        accs1 = __builtin_amdgcn_mfma_f32_32x32x16_bf16(kf1, qf[t], accs1, 0, 0, 0);
      }
      __builtin_amdgcn_s_setprio(0);

      if (kb >= 2 * qt) {
        const int kbase = kb * 64 + 4 * h;
#pragma unroll
        for (int reg = 0; reg < 16; ++reg) {
          const int k0 = kbase + (reg & 3) + 8 * (reg >> 2);
          if (k0 > qg)      accs0[reg] = -1e30f;
          if (k0 + 32 > qg) accs1[reg] = -1e30f;
        }
      }

      float mx = -1e30f;
#pragma unroll
      for (int reg = 0; reg < 16; ++reg)
        mx = fmaxf(mx, fmaxf(accs0[reg], accs1[reg]));
      if (!__all(mx <= m + 8.f)) {
        float mxo = __shfl_xor(mx, 32, 64);
        float mnew = fmaxf(m, fmaxf(mx, mxo));
        float corr = exp2a(m - mnew);
        m = mnew;
        lpart *= corr;
#pragma unroll
        for (int reg = 0; reg < 16; ++reg) {
          const int crow = (reg & 3) + 8 * (reg >> 2) + 4 * h;
          float cw = __shfl(corr, crow, 64);
#pragma unroll
          for (int dj = 0; dj < 4; ++dj) acc_o[dj][reg] *= cw;
        }
      }

      bf16x8 pa[4];
#pragma unroll
      for (int ks = 0; ks < 4; ++ks) {
        float e[8];
#pragma unroll
        for (int j = 0; j < 8; ++j) {
          float s = (ks < 2) ? accs0[8 * (ks & 1) + j] : accs1[8 * (ks & 1) + j];
          e[j] = exp2a(s - m);
          lpart += e[j];
        }
        unsigned w01 = cvtpk(e[0], e[1]);
        unsigned w23 = cvtpk(e[2], e[3]);
        unsigned w45 = cvtpk(e[4], e[5]);
        unsigned w67 = cvtpk(e[6], e[7]);
        asm volatile("v_permlane32_swap_b32 %0, %1" : "+v"(w01), "+v"(w45));
        asm volatile("v_permlane32_swap_b32 %0, %1" : "+v"(w23), "+v"(w67));
        union { unsigned u[4]; bf16x8 v; } pu;
        pu.u[0] = w01; pu.u[1] = w23; pu.u[2] = w45; pu.u[3] = w67;
        pa[ks] = pu.v;
      }

      __builtin_amdgcn_s_setprio(1);
#pragma unroll
      for (int dj = 0; dj < 4; ++dj) {
        const int vrow = (dj * 32 + q31) << 7;
#pragma unroll
        for (int ks = 0; ks < 4; ++ks) {
          bf16x8 vf = ld8b(Vc, (vrow + ks * 32 + h * 16) ^ vswz);
          acc_o[dj] = __builtin_amdgcn_mfma_f32_32x32x16_bf16(pa[ks], vf, acc_o[dj], 0, 0, 0);
        }
      }
      __builtin_amdgcn_s_setprio(0);

      __syncthreads();
    }

    float lsum = lpart + __shfl_xor(lpart, 32, 64);
    float linv = 1.f / lsum;
#pragma unroll
    for (int reg = 0; reg < 16; ++reg) {
      const int crow = (reg & 3) + 8 * (reg >> 2) + 4 * h;
      float lv = __shfl(linv, crow, 64);
      size_t rowoff =
          (size_t)(b * S_ + qt * 128 + wave * 32 + crow) * (H_ * HD_) + hh * HD_ + q31;
#pragma unroll
      for (int dj = 0; dj < 4; ++dj)
        O[rowoff + dj * 32] = f2bf(acc_o[dj][reg] * lv);
    }
  }
}

// Diagnostic: if ws_size is too small, fill fp32 output with sentinel 12345.
__global__ void fill_sentinel(float* __restrict__ O, int n) {
  int i = blockIdx.x * 256 + threadIdx.x;
  if (i < n) O[i] = 12345.0f;
}

// ---------------------------------------------------------------------------
extern "C" void kernel_launch(void* const* d_in, const int* in_sizes, int n_in,
                              void* d_out, int out_size, void* d_ws, size_t ws_size,
                              hipStream_t stream) {
  const float* hidden = (const float*)d_in[0]; // [B,S,D] fp32
  const float* wqkv   = (const float*)d_in[1]; // [6144,4096] fp32
  const float* wdense = (const float*)d_in[2]; // [4096,4096] fp32
  float* out = (float*)d_out;                  // [B,S,4096] fp32

  const size_t NEED = 134217728;
  if (ws_size < NEED) {
    fill_sentinel<<<dim3((out_size + 255) / 256), dim3(256), 0, stream>>>(out, out_size);
    return;
  }

  char* ws = (char*)d_ws;
  // Phase 1 layout
  unsigned short* Hb    = (unsigned short*)(ws);                 // 33,554,432 B
  unsigned short* Wqb   = (unsigned short*)(ws + 33554432);      // 50,331,648 B
  unsigned short* fused = (unsigned short*)(ws + 83886080);      // 50,331,648 B
  // Phase 2 layout (after GEMM1: Hb/Wqb dead; Wdb written AFTER GEMM1!)
  unsigned short* Qr    = (unsigned short*)(ws);                 // 33,554,432 B
  unsigned short* Kr    = (unsigned short*)(ws + 33554432);      //  8,388,608 B
  unsigned short* Vt    = (unsigned short*)(ws + 41943040);      //  8,388,608 B
  unsigned short* Wdb   = (unsigned short*)(ws + 50331648);      // 33,554,432 B
  unsigned short* attn_out = (unsigned short*)(ws + 83886080);   // 33,554,432 B (over fused)

  const int nH4 = B_ * S_ * D_ / 4;   // 4,194,304
  const int nQ4 = NE_ * D_ / 4;       // 6,291,456
  const int nD4 = D_ * D_ / 4;        // 4,194,304

  cvt2_f32_bf16<<<dim3((nH4 + nQ4 + 255) / 256), dim3(256), 0, stream>>>(
      hidden, Hb, nH4, wqkv, Wqb, nQ4);

  gemm256<unsigned short, 192><<<dim3(NE_ / 192, (B_ * S_) / 256), dim3(512), 0, stream>>>(
      Hb, Wqb, fused, B_ * S_, NE_);

  rope_scatter_cvt<<<dim3((ROPE_N + nD4 + 255) / 256), dim3(256), 0, stream>>>(
      fused, Qr, Kr, Vt, wdense, Wdb, nD4);

  attn_fwd<<<dim3(8, H_, B_), dim3(256), 0, stream>>>(Qr, Kr, Vt, attn_out);

  gemm256<float, 256><<<dim3(D_ / 256, (B_ * S_) / 256), dim3(512), 0, stream>>>(
      attn_out, Wdb, out, B_ * S_, D_);
}